// Round 1
// baseline (1490.370 us; speedup 1.0000x reference)
//
#include <hip/hip_runtime.h>
#include <cstdint>
#include <cstddef>

// Problem constants
#define B_SZ 8
#define L_SZ 1024
#define F_SZ 1024
#define H_SZ 16
#define D_SZ 64
#define M_SZ (B_SZ * L_SZ)  // 8192 rows

// ---------------------------------------------------------------------------
// GEMM: C[M x 1024] = A[M x 1024] @ W[1024 x 1024], fp32, 128x128x8 tiles,
// 256 threads, 8x8 micro-tile per thread. Prefetch next k-slice during compute.
// ---------------------------------------------------------------------------
#define BM 128
#define BN 128
#define BK 8

__device__ __forceinline__ void gemm_body(const float* __restrict__ A,
                                          const float* __restrict__ W,
                                          float* __restrict__ C) {
  // As transposed [k][m], pad +4 floats: bank = (4k+m)%32 -> worst 2-way (free)
  alignas(16) __shared__ float As[BK][BM + 4];
  alignas(16) __shared__ float Bs[BK][BN + 4];
  const int tid = threadIdx.x;
  const int tx = tid & 15;   // 16 col-threads
  const int ty = tid >> 4;   // 16 row-threads
  const int bn = blockIdx.x * BN;
  const int bm = blockIdx.y * BM;

  const int a_m = tid >> 1;         // 0..127
  const int a_k = (tid & 1) << 2;   // 0 or 4
  const int b_k = tid >> 5;         // 0..7
  const int b_n = (tid & 31) << 2;  // 0..124

  const float* Ap = A + (size_t)(bm + a_m) * F_SZ + a_k;
  const float* Wp = W + (size_t)b_k * F_SZ + bn + b_n;

  float acc[8][8];
#pragma unroll
  for (int i = 0; i < 8; ++i)
#pragma unroll
    for (int j = 0; j < 8; ++j) acc[i][j] = 0.f;

  float4 av = *(const float4*)Ap;
  float4 bv = *(const float4*)Wp;

  for (int k0 = 0; k0 < F_SZ; k0 += BK) {
    __syncthreads();  // previous tile's LDS reads complete
    As[a_k + 0][a_m] = av.x;
    As[a_k + 1][a_m] = av.y;
    As[a_k + 2][a_m] = av.z;
    As[a_k + 3][a_m] = av.w;
    *(float4*)&Bs[b_k][b_n] = bv;
    __syncthreads();
    if (k0 + BK < F_SZ) {  // issue next tile's loads early; overlap with FMAs
      av = *(const float4*)(Ap + k0 + BK);
      bv = *(const float4*)(Wp + (size_t)(k0 + BK) * F_SZ);
    }
#pragma unroll
    for (int k = 0; k < BK; ++k) {
      const float4 a0 = *(const float4*)&As[k][ty * 8];
      const float4 a1 = *(const float4*)&As[k][ty * 8 + 4];
      const float4 b0 = *(const float4*)&Bs[k][tx * 8];
      const float4 b1 = *(const float4*)&Bs[k][tx * 8 + 4];
      const float ar[8] = {a0.x, a0.y, a0.z, a0.w, a1.x, a1.y, a1.z, a1.w};
      const float br[8] = {b0.x, b0.y, b0.z, b0.w, b1.x, b1.y, b1.z, b1.w};
#pragma unroll
      for (int i = 0; i < 8; ++i)
#pragma unroll
        for (int j = 0; j < 8; ++j)
          acc[i][j] = fmaf(ar[i], br[j], acc[i][j]);
    }
  }

#pragma unroll
  for (int i = 0; i < 8; ++i) {
    float* crow = C + (size_t)(bm + ty * 8 + i) * F_SZ + bn + tx * 8;
    *(float4*)crow = make_float4(acc[i][0], acc[i][1], acc[i][2], acc[i][3]);
    *(float4*)(crow + 4) = make_float4(acc[i][4], acc[i][5], acc[i][6], acc[i][7]);
  }
}

// Fused QKV: z=0 -> Q = q@Wq, z=1 -> K = kv@Wk, z=2 -> V = kv@Wv
__global__ __launch_bounds__(256) void gemm_qkv(
    const float* __restrict__ q, const float* __restrict__ kv,
    const float* __restrict__ Wq, const float* __restrict__ Wk,
    const float* __restrict__ Wv, float* __restrict__ Qb,
    float* __restrict__ Kb, float* __restrict__ Vb) {
  const int z = blockIdx.z;
  const float* A = (z == 0) ? q : kv;
  const float* W = (z == 0) ? Wq : (z == 1) ? Wk : Wv;
  float* C = (z == 0) ? Qb : (z == 1) ? Kb : Vb;
  gemm_body(A, W, C);
}

__global__ __launch_bounds__(256) void gemm_one(const float* __restrict__ A,
                                                const float* __restrict__ W,
                                                float* __restrict__ C) {
  gemm_body(A, W, C);
}

// ---------------------------------------------------------------------------
// LayerNorm in-place over last dim (1024). One block per row; y picks buffer.
// ---------------------------------------------------------------------------
__global__ __launch_bounds__(256) void ln_kernel(
    float* __restrict__ Qb, float* __restrict__ Kb, float* __restrict__ Vb,
    const float* __restrict__ sq, const float* __restrict__ bq,
    const float* __restrict__ sk, const float* __restrict__ bk,
    const float* __restrict__ sv, const float* __restrict__ bv) {
  const int z = blockIdx.y;
  float* buf = (z == 0) ? Qb : (z == 1) ? Kb : Vb;
  const float* sc = (z == 0) ? sq : (z == 1) ? sk : sv;
  const float* bi = (z == 0) ? bq : (z == 1) ? bk : bv;

  float* row = buf + (size_t)blockIdx.x * F_SZ;
  const int tid = threadIdx.x;
  float4 v = *(const float4*)(row + tid * 4);
  float s = v.x + v.y + v.z + v.w;
  float ss = v.x * v.x + v.y * v.y + v.z * v.z + v.w * v.w;
#pragma unroll
  for (int off = 1; off < 64; off <<= 1) {
    s += __shfl_xor(s, off, 64);
    ss += __shfl_xor(ss, off, 64);
  }
  __shared__ float red[2][4];
  if ((tid & 63) == 0) {
    red[0][tid >> 6] = s;
    red[1][tid >> 6] = ss;
  }
  __syncthreads();
  s = red[0][0] + red[0][1] + red[0][2] + red[0][3];
  ss = red[1][0] + red[1][1] + red[1][2] + red[1][3];
  const float mu = s * (1.f / F_SZ);
  const float var = ss * (1.f / F_SZ) - mu * mu;
  const float r = rsqrtf(var + 1e-6f);
  const float4 scv = *(const float4*)(sc + tid * 4);
  const float4 biv = *(const float4*)(bi + tid * 4);
  v.x = (v.x - mu) * r * scv.x + biv.x;
  v.y = (v.y - mu) * r * scv.y + biv.y;
  v.z = (v.z - mu) * r * scv.z + biv.z;
  v.w = (v.w - mu) * r * scv.w + biv.w;
  *(float4*)(row + tid * 4) = v;
}

// ---------------------------------------------------------------------------
// Flash attention, fp32. Block = (q-tile of 64 rows, head, batch), 256 threads.
// Thread (ty,tx) owns a 4x4 patch: rows 4ty.., cols 4tx.. of the 64x64 tiles.
// KPt union'd: K^T during S-phase, P^T during PV-phase (keeps LDS = 52KB < 64KB).
// Output written IN PLACE over the Q buffer (each block only touches the
// Q rows x head-cols it alone reads).
// ---------------------------------------------------------------------------
__global__ __launch_bounds__(256) void attn_kernel(
    float* __restrict__ QOb, const float* __restrict__ Kb,
    const float* __restrict__ Vb, const float* __restrict__ mask) {
  alignas(16) __shared__ float Qt[64][68];   // [d][i]  (transposed)
  alignas(16) __shared__ float KPt[64][68];  // S-phase: K^T [d][j]; PV: P^T [j][i]
  alignas(16) __shared__ float Vs[64][68];   // [j][c]
  const int tid = threadIdx.x;
  const int tx = tid & 15;
  const int ty = tid >> 4;
  const int q0 = blockIdx.x * 64;
  const int h = blockIdx.y;
  const int b = blockIdx.z;
  const size_t base = (size_t)b * L_SZ * F_SZ + (size_t)h * D_SZ;

  const int li = tid >> 2;        // 0..63 row within tile
  const int ld = (tid & 3) << 4;  // 0,16,32,48 col-chunk

  {  // load Q tile transposed
    const float* qp = QOb + base + (size_t)(q0 + li) * F_SZ + ld;
#pragma unroll
    for (int c = 0; c < 4; ++c) {
      const float4 v = *(const float4*)(qp + 4 * c);
      Qt[ld + 4 * c + 0][li] = v.x;
      Qt[ld + 4 * c + 1][li] = v.y;
      Qt[ld + 4 * c + 2][li] = v.z;
      Qt[ld + 4 * c + 3][li] = v.w;
    }
  }

  float mrow[4], lrow[4], acc[4][4];
#pragma unroll
  for (int a = 0; a < 4; ++a) {
    mrow[a] = -3.0e38f;
    lrow[a] = 0.f;
#pragma unroll
    for (int c = 0; c < 4; ++c) acc[a][c] = 0.f;
  }

  float4 kr[4], vr[4];  // prefetch registers for K/V tiles
  {
    const float* kp = Kb + base + (size_t)li * F_SZ + ld;
    const float* vp = Vb + base + (size_t)li * F_SZ + ld;
#pragma unroll
    for (int c = 0; c < 4; ++c) {
      kr[c] = *(const float4*)(kp + 4 * c);
      vr[c] = *(const float4*)(vp + 4 * c);
    }
  }

  for (int kt = 0; kt < 16; ++kt) {
    const int k0 = kt * 64;
    __syncthreads();  // b1: prev PV reads of KPt/Vs done
#pragma unroll
    for (int c = 0; c < 4; ++c) {
      KPt[ld + 4 * c + 0][li] = kr[c].x;
      KPt[ld + 4 * c + 1][li] = kr[c].y;
      KPt[ld + 4 * c + 2][li] = kr[c].z;
      KPt[ld + 4 * c + 3][li] = kr[c].w;
      *(float4*)&Vs[li][ld + 4 * c] = vr[c];
    }
    __syncthreads();  // b2: tiles visible
    if (kt < 15) {    // prefetch next K/V during S-phase
      const float* kp = Kb + base + (size_t)(k0 + 64 + li) * F_SZ + ld;
      const float* vp = Vb + base + (size_t)(k0 + 64 + li) * F_SZ + ld;
#pragma unroll
      for (int c = 0; c < 4; ++c) {
        kr[c] = *(const float4*)(kp + 4 * c);
        vr[c] = *(const float4*)(vp + 4 * c);
      }
    }
    // S = Q K^T (4x4 per thread)
    float s[4][4];
#pragma unroll
    for (int a = 0; a < 4; ++a)
#pragma unroll
      for (int j = 0; j < 4; ++j) s[a][j] = 0.f;
#pragma unroll 8
    for (int d = 0; d < 64; ++d) {
      const float4 qv = *(const float4*)&Qt[d][ty * 4];
      const float4 kv = *(const float4*)&KPt[d][tx * 4];
      const float ar[4] = {qv.x, qv.y, qv.z, qv.w};
      const float br[4] = {kv.x, kv.y, kv.z, kv.w};
#pragma unroll
      for (int a = 0; a < 4; ++a)
#pragma unroll
        for (int j = 0; j < 4; ++j) s[a][j] = fmaf(ar[a], br[j], s[a][j]);
    }
    __syncthreads();  // b3: all S-phase reads of KPt done before P^T overwrites

    // scale + mask + online softmax; store P^T into KPt
#pragma unroll
    for (int a = 0; a < 4; ++a) {
      const float4 mk =
          *(const float4*)(mask + (size_t)(q0 + ty * 4 + a) * L_SZ + k0 + tx * 4);
      s[a][0] = fmaf(s[a][0], 0.125f, mk.x);
      s[a][1] = fmaf(s[a][1], 0.125f, mk.y);
      s[a][2] = fmaf(s[a][2], 0.125f, mk.z);
      s[a][3] = fmaf(s[a][3], 0.125f, mk.w);
      float mx = fmaxf(fmaxf(s[a][0], s[a][1]), fmaxf(s[a][2], s[a][3]));
#pragma unroll
      for (int off = 1; off < 16; off <<= 1)
        mx = fmaxf(mx, __shfl_xor(mx, off, 64));
      const float mnew = fmaxf(mrow[a], mx);
      const float alpha = __expf(mrow[a] - mnew);
      mrow[a] = mnew;
      float rs = 0.f;
#pragma unroll
      for (int j = 0; j < 4; ++j) {
        s[a][j] = __expf(s[a][j] - mnew);
        rs += s[a][j];
      }
#pragma unroll
      for (int off = 1; off < 16; off <<= 1) rs += __shfl_xor(rs, off, 64);
      lrow[a] = lrow[a] * alpha + rs;
#pragma unroll
      for (int c = 0; c < 4; ++c) acc[a][c] *= alpha;
#pragma unroll
      for (int j = 0; j < 4; ++j) KPt[tx * 4 + j][ty * 4 + a] = s[a][j];
    }
    __syncthreads();  // b4: P^T visible

    // O += P V
#pragma unroll 8
    for (int j = 0; j < 64; ++j) {
      const float4 pv = *(const float4*)&KPt[j][ty * 4];
      const float4 vv = *(const float4*)&Vs[j][tx * 4];
      const float pr[4] = {pv.x, pv.y, pv.z, pv.w};
      const float vc[4] = {vv.x, vv.y, vv.z, vv.w};
#pragma unroll
      for (int a = 0; a < 4; ++a)
#pragma unroll
        for (int c = 0; c < 4; ++c) acc[a][c] = fmaf(pr[a], vc[c], acc[a][c]);
    }
  }

  // normalize + write in place over Q
#pragma unroll
  for (int a = 0; a < 4; ++a) {
    const float inv = 1.f / lrow[a];
    *(float4*)(QOb + base + (size_t)(q0 + ty * 4 + a) * F_SZ + tx * 4) =
        make_float4(acc[a][0] * inv, acc[a][1] * inv, acc[a][2] * inv,
                    acc[a][3] * inv);
  }
}

// ---------------------------------------------------------------------------
extern "C" void kernel_launch(void* const* d_in, const int* in_sizes, int n_in,
                              void* d_out, int out_size, void* d_ws,
                              size_t ws_size, hipStream_t stream) {
  const float* kv = (const float*)d_in[0];
  const float* q = (const float*)d_in[1];
  const float* mask = (const float*)d_in[2];
  const float* Wq = (const float*)d_in[3];
  const float* Wk = (const float*)d_in[4];
  const float* Wv = (const float*)d_in[5];
  const float* Wo = (const float*)d_in[6];
  const float* lqs = (const float*)d_in[7];
  const float* lqb = (const float*)d_in[8];
  const float* lks = (const float*)d_in[9];
  const float* lkb = (const float*)d_in[10];
  const float* lvs = (const float*)d_in[11];
  const float* lvb = (const float*)d_in[12];
  float* out = (float*)d_out;

  // workspace: Q | K | V, each 8192*1024 fp32 (32MB) -> 96MB total.
  float* Qb = (float*)d_ws;
  float* Kb = Qb + (size_t)M_SZ * F_SZ;
  float* Vb = Kb + (size_t)M_SZ * F_SZ;

  // 1) QKV projections (fused over z)
  gemm_qkv<<<dim3(F_SZ / BN, M_SZ / BM, 3), 256, 0, stream>>>(q, kv, Wq, Wk, Wv,
                                                              Qb, Kb, Vb);
  // 2) LayerNorm in place (y: 0=Q,1=K,2=V)
  ln_kernel<<<dim3(M_SZ, 3), 256, 0, stream>>>(Qb, Kb, Vb, lqs, lqb, lks, lkb,
                                               lvs, lvb);
  // 3) flash attention; writes output in place over Qb
  attn_kernel<<<dim3(L_SZ / 64, H_SZ, B_SZ), 256, 0, stream>>>(Qb, Kb, Vb, mask);
  // 4) output projection -> d_out
  gemm_one<<<dim3(F_SZ / BN, M_SZ / BM, 1), 256, 0, stream>>>(Qb, Wo, out);
}

// Round 4
// 1326.229 us; speedup vs baseline: 1.1238x; 1.1238x over previous
//
#include <hip/hip_runtime.h>
#include <cstdint>
#include <cstddef>

// Problem constants
#define B_SZ 8
#define L_SZ 1024
#define F_SZ 1024
#define H_SZ 16
#define D_SZ 64
#define M_SZ (B_SZ * L_SZ)  // 8192 rows

typedef __attribute__((ext_vector_type(8))) short bf16x8;
typedef __attribute__((ext_vector_type(4))) float f32x4;

// ---------------------------------------------------------------------------
// fp32 -> (hi, lo) bf16 split. hi = truncated top-16 bits (exact residual),
// lo = RNE-bf16 of (x - hi). x ~= hi + lo with ~2^-17 relative error.
// ---------------------------------------------------------------------------
__device__ __forceinline__ void split1(float x, unsigned short& h,
                                       unsigned short& l) {
  const unsigned xb = __float_as_uint(x);
  h = (unsigned short)(xb >> 16);
  const float lf = x - __uint_as_float(xb & 0xFFFF0000u);
  const unsigned lb = __float_as_uint(lf);
  l = (unsigned short)((lb + 0x7FFFu + ((lb >> 16) & 1u)) >> 16);
}

__device__ __forceinline__ void gld16(const void* g, void* l) {
  __builtin_amdgcn_global_load_lds(
      (const __attribute__((address_space(1))) void*)g,
      (__attribute__((address_space(3))) void*)l, 16, 0, 0);
}

// ---------------------------------------------------------------------------
// bf16x3 MFMA GEMM: C[128x128 tile] = A @ B^T_storage, both operands stored
// row-major [rows][K=1024] as hi/lo bf16 pairs. 256 thr = 4 waves, each wave
// a 64x64 quadrant = 4x4 fragments of 16x16, K-step 32 (one mfma_16x16x32
// per fragment per pass; 3 passes: hh, hl, lh).
// LDS chunk-major: slot s = kchunk*128 + row holds 8 bf16 (16B), so
// consecutive lanes read consecutive 16B slots (conflict-free).
// ---------------------------------------------------------------------------
__device__ __forceinline__ void gemm_x3_body(const unsigned short* __restrict__ Ah,
                                             const unsigned short* __restrict__ Al,
                                             const unsigned short* __restrict__ Bh,
                                             const unsigned short* __restrict__ Bl,
                                             float* __restrict__ C) {
  __shared__ bf16x8 sT[4][512];  // Ahi, Alo, Bhi, Blo tiles, 8KB each
  const int tid = threadIdx.x;
  const int lane = tid & 63;
  const int wave = tid >> 6;
  const int wr = wave >> 1, wc = wave & 1;
  const int lg = lane >> 4, lr = lane & 15;
  const int bn = blockIdx.x * 128;
  const int bm = blockIdx.y * 128;

  // staging: wave w owns tile w (0:Ahi 1:Alo 2:Bhi 3:Blo)
  const unsigned short* gsrc = (wave == 0) ? Ah
                               : (wave == 1) ? Al
                               : (wave == 2) ? Bh
                                             : Bl;
  const int rowbase = (wave < 2) ? bm : bn;
  bf16x8* tile = sT[wave];
  const unsigned short* gw = gsrc + (size_t)(rowbase + lane) * 1024;

  f32x4 acc[4][4];
#pragma unroll
  for (int i = 0; i < 4; ++i)
#pragma unroll
    for (int j = 0; j < 4; ++j) acc[i][j] = {0.f, 0.f, 0.f, 0.f};

  for (int k0 = 0; k0 < 1024; k0 += 32) {
    __syncthreads();  // prior LDS reads done
#pragma unroll
    for (int q = 0; q < 8; ++q) {
      // instr q: lanes cover rows (q&1)*64+lane, k-chunk q>>1 (8 bf16 = 16B)
      const unsigned short* gp = gw + (size_t)(q & 1) * 64 * 1024 + (q >> 1) * 8 + k0;
      gld16(gp, &tile[q * 64]);
    }
    __syncthreads();  // compiler drains vmcnt(0) before s_barrier

    bf16x8 ah[4], al[4], bh[4], bl[4];
#pragma unroll
    for (int i = 0; i < 4; ++i) {
      const int s = lg * 128 + wr * 64 + i * 16 + lr;
      ah[i] = sT[0][s];
      al[i] = sT[1][s];
    }
#pragma unroll
    for (int j = 0; j < 4; ++j) {
      const int s = lg * 128 + wc * 64 + j * 16 + lr;
      bh[j] = sT[2][s];
      bl[j] = sT[3][s];
    }
#pragma unroll
    for (int i = 0; i < 4; ++i)
#pragma unroll
      for (int j = 0; j < 4; ++j) {
        acc[i][j] = __builtin_amdgcn_mfma_f32_16x16x32_bf16(ah[i], bh[j],
                                                            acc[i][j], 0, 0, 0);
        acc[i][j] = __builtin_amdgcn_mfma_f32_16x16x32_bf16(ah[i], bl[j],
                                                            acc[i][j], 0, 0, 0);
        acc[i][j] = __builtin_amdgcn_mfma_f32_16x16x32_bf16(al[i], bh[j],
                                                            acc[i][j], 0, 0, 0);
      }
  }

  // C/D layout (m89-verified): col = lane&15, row = (lane>>4)*4 + reg
  const int r0 = bm + wr * 64 + lg * 4;
  const int c0 = bn + wc * 64 + lr;
#pragma unroll
  for (int i = 0; i < 4; ++i)
#pragma unroll
    for (int j = 0; j < 4; ++j) {
      float* cp = C + (size_t)(r0 + i * 16) * 1024 + c0 + j * 16;
      cp[0] = acc[i][j][0];
      cp[1024] = acc[i][j][1];
      cp[2048] = acc[i][j][2];
      cp[3072] = acc[i][j][3];
    }
}

__global__ __launch_bounds__(256) void gemm_x3_qkv(
    const unsigned short* __restrict__ qh, const unsigned short* __restrict__ ql,
    const unsigned short* __restrict__ kvh, const unsigned short* __restrict__ kvl,
    const unsigned short* __restrict__ Whi, const unsigned short* __restrict__ Wlo,
    float* __restrict__ Qb, float* __restrict__ Kb, float* __restrict__ Vb) {
  const int z = blockIdx.z;
  const unsigned short* Ah = (z == 0) ? qh : kvh;
  const unsigned short* Al = (z == 0) ? ql : kvl;
  const unsigned short* Bh = Whi + (size_t)z * (1024 * 1024);
  const unsigned short* Bl = Wlo + (size_t)z * (1024 * 1024);
  float* C = (z == 0) ? Qb : (z == 1) ? Kb : Vb;
  gemm_x3_body(Ah, Al, Bh, Bl, C);
}

__global__ __launch_bounds__(256) void gemm_x3_one(
    const unsigned short* __restrict__ Ah, const unsigned short* __restrict__ Al,
    const unsigned short* __restrict__ Bh, const unsigned short* __restrict__ Bl,
    float* __restrict__ C) {
  gemm_x3_body(Ah, Al, Bh, Bl, C);
}

// ---------------------------------------------------------------------------
// Weight split + transpose: W[K=1024][N=1024] fp32 -> Wt hi/lo [N][K] bf16.
// z picks weight {Wq,Wk,Wv,Wo}; outputs at z*1M elements.
// ---------------------------------------------------------------------------
__global__ __launch_bounds__(256) void split_w(
    const float* __restrict__ Wq, const float* __restrict__ Wk,
    const float* __restrict__ Wv, const float* __restrict__ Wo,
    unsigned short* __restrict__ Whi, unsigned short* __restrict__ Wlo) {
  const int z = blockIdx.z;
  const float* W = (z == 0) ? Wq : (z == 1) ? Wk : (z == 2) ? Wv : Wo;
  unsigned short* oh = Whi + (size_t)z * (1024 * 1024);
  unsigned short* ol = Wlo + (size_t)z * (1024 * 1024);
  __shared__ float t[32][33];
  const int k0 = blockIdx.y * 32, n0 = blockIdx.x * 32;
  const int tid = threadIdx.x;
  const int r = tid >> 3, c4 = (tid & 7) * 4;
  const float4 v = *(const float4*)&W[(size_t)(k0 + r) * 1024 + n0 + c4];
  t[r][c4 + 0] = v.x;
  t[r][c4 + 1] = v.y;
  t[r][c4 + 2] = v.z;
  t[r][c4 + 3] = v.w;
  __syncthreads();
  ushort4 h4, l4;
  split1(t[c4 + 0][r], h4.x, l4.x);
  split1(t[c4 + 1][r], h4.y, l4.y);
  split1(t[c4 + 2][r], h4.z, l4.z);
  split1(t[c4 + 3][r], h4.w, l4.w);
  const size_t o = (size_t)(n0 + r) * 1024 + k0 + c4;
  *(ushort4*)&oh[o] = h4;
  *(ushort4*)&ol[o] = l4;
}

// A-matrix split (no transpose): z=0 kv -> (kvh,kvl); z=1 q -> (qh,ql)
__global__ __launch_bounds__(256) void split_a(
    const float* __restrict__ kv, const float* __restrict__ q,
    unsigned short* __restrict__ kvh, unsigned short* __restrict__ kvl,
    unsigned short* __restrict__ qh, unsigned short* __restrict__ ql) {
  const int z = blockIdx.y;
  const float* src = (z == 0) ? kv : q;
  unsigned short* dh = (z == 0) ? kvh : qh;
  unsigned short* dl = (z == 0) ? kvl : ql;
  const size_t idx = (size_t)blockIdx.x * 256 + threadIdx.x;
  const float4 v = ((const float4*)src)[idx];
  ushort4 h4, l4;
  split1(v.x, h4.x, l4.x);
  split1(v.y, h4.y, l4.y);
  split1(v.z, h4.z, l4.z);
  split1(v.w, h4.w, l4.w);
  ((ushort4*)dh)[idx] = h4;
  ((ushort4*)dl)[idx] = l4;
}

// ---------------------------------------------------------------------------
// fp32 GEMM (round-1 fallback path)
// ---------------------------------------------------------------------------
#define BM 128
#define BN 128
#define BK 8

__device__ __forceinline__ void gemm_body(const float* __restrict__ A,
                                          const float* __restrict__ W,
                                          float* __restrict__ C) {
  alignas(16) __shared__ float As[BK][BM + 4];
  alignas(16) __shared__ float Bs[BK][BN + 4];
  const int tid = threadIdx.x;
  const int tx = tid & 15;
  const int ty = tid >> 4;
  const int bn = blockIdx.x * BN;
  const int bm = blockIdx.y * BM;

  const int a_m = tid >> 1;
  const int a_k = (tid & 1) << 2;
  const int b_k = tid >> 5;
  const int b_n = (tid & 31) << 2;

  const float* Ap = A + (size_t)(bm + a_m) * F_SZ + a_k;
  const float* Wp = W + (size_t)b_k * F_SZ + bn + b_n;

  float acc[8][8];
#pragma unroll
  for (int i = 0; i < 8; ++i)
#pragma unroll
    for (int j = 0; j < 8; ++j) acc[i][j] = 0.f;

  float4 av = *(const float4*)Ap;
  float4 bv = *(const float4*)Wp;

  for (int k0 = 0; k0 < F_SZ; k0 += BK) {
    __syncthreads();
    As[a_k + 0][a_m] = av.x;
    As[a_k + 1][a_m] = av.y;
    As[a_k + 2][a_m] = av.z;
    As[a_k + 3][a_m] = av.w;
    *(float4*)&Bs[b_k][b_n] = bv;
    __syncthreads();
    if (k0 + BK < F_SZ) {
      av = *(const float4*)(Ap + k0 + BK);
      bv = *(const float4*)(Wp + (size_t)(k0 + BK) * F_SZ);
    }
#pragma unroll
    for (int k = 0; k < BK; ++k) {
      const float4 a0 = *(const float4*)&As[k][ty * 8];
      const float4 a1 = *(const float4*)&As[k][ty * 8 + 4];
      const float4 b0 = *(const float4*)&Bs[k][tx * 8];
      const float4 b1 = *(const float4*)&Bs[k][tx * 8 + 4];
      const float ar[8] = {a0.x, a0.y, a0.z, a0.w, a1.x, a1.y, a1.z, a1.w};
      const float br[8] = {b0.x, b0.y, b0.z, b0.w, b1.x, b1.y, b1.z, b1.w};
#pragma unroll
      for (int i = 0; i < 8; ++i)
#pragma unroll
        for (int j = 0; j < 8; ++j)
          acc[i][j] = fmaf(ar[i], br[j], acc[i][j]);
    }
  }

#pragma unroll
  for (int i = 0; i < 8; ++i) {
    float* crow = C + (size_t)(bm + ty * 8 + i) * F_SZ + bn + tx * 8;
    *(float4*)crow = make_float4(acc[i][0], acc[i][1], acc[i][2], acc[i][3]);
    *(float4*)(crow + 4) = make_float4(acc[i][4], acc[i][5], acc[i][6], acc[i][7]);
  }
}

__global__ __launch_bounds__(256) void gemm_qkv(
    const float* __restrict__ q, const float* __restrict__ kv,
    const float* __restrict__ Wq, const float* __restrict__ Wk,
    const float* __restrict__ Wv, float* __restrict__ Qb,
    float* __restrict__ Kb, float* __restrict__ Vb) {
  const int z = blockIdx.z;
  const float* A = (z == 0) ? q : kv;
  const float* W = (z == 0) ? Wq : (z == 1) ? Wk : Wv;
  float* C = (z == 0) ? Qb : (z == 1) ? Kb : Vb;
  gemm_body(A, W, C);
}

__global__ __launch_bounds__(256) void gemm_one(const float* __restrict__ A,
                                                const float* __restrict__ W,
                                                float* __restrict__ C) {
  gemm_body(A, W, C);
}

// ---------------------------------------------------------------------------
// LayerNorm in-place over last dim (1024). One block per row; y picks buffer.
// ---------------------------------------------------------------------------
__global__ __launch_bounds__(256) void ln_kernel(
    float* __restrict__ Qb, float* __restrict__ Kb, float* __restrict__ Vb,
    const float* __restrict__ sq, const float* __restrict__ bq,
    const float* __restrict__ sk, const float* __restrict__ bk,
    const float* __restrict__ sv, const float* __restrict__ bv) {
  const int z = blockIdx.y;
  float* buf = (z == 0) ? Qb : (z == 1) ? Kb : Vb;
  const float* sc = (z == 0) ? sq : (z == 1) ? sk : sv;
  const float* bi = (z == 0) ? bq : (z == 1) ? bk : bv;

  float* row = buf + (size_t)blockIdx.x * F_SZ;
  const int tid = threadIdx.x;
  float4 v = *(const float4*)(row + tid * 4);
  float s = v.x + v.y + v.z + v.w;
  float ss = v.x * v.x + v.y * v.y + v.z * v.z + v.w * v.w;
#pragma unroll
  for (int off = 1; off < 64; off <<= 1) {
    s += __shfl_xor(s, off, 64);
    ss += __shfl_xor(ss, off, 64);
  }
  __shared__ float red[2][4];
  if ((tid & 63) == 0) {
    red[0][tid >> 6] = s;
    red[1][tid >> 6] = ss;
  }
  __syncthreads();
  s = red[0][0] + red[0][1] + red[0][2] + red[0][3];
  ss = red[1][0] + red[1][1] + red[1][2] + red[1][3];
  const float mu = s * (1.f / F_SZ);
  const float var = ss * (1.f / F_SZ) - mu * mu;
  const float r = rsqrtf(var + 1e-6f);
  const float4 scv = *(const float4*)(sc + tid * 4);
  const float4 biv = *(const float4*)(bi + tid * 4);
  v.x = (v.x - mu) * r * scv.x + biv.x;
  v.y = (v.y - mu) * r * scv.y + biv.y;
  v.z = (v.z - mu) * r * scv.z + biv.z;
  v.w = (v.w - mu) * r * scv.w + biv.w;
  *(float4*)(row + tid * 4) = v;
}

// ---------------------------------------------------------------------------
// Flash attention, fp32. SPLIT=0: write fp32 in place over Q (fallback).
// SPLIT=1: write hi/lo bf16 split of the output (feeds Wo MFMA GEMM).
// ---------------------------------------------------------------------------
template <int SPLIT>
__global__ __launch_bounds__(256) void attn_kernel(
    float* __restrict__ QOb, const float* __restrict__ Kb,
    const float* __restrict__ Vb, const float* __restrict__ mask,
    unsigned short* __restrict__ AOhi, unsigned short* __restrict__ AOlo) {
  alignas(16) __shared__ float Qt[64][68];   // [d][i]  (transposed)
  alignas(16) __shared__ float KPt[64][68];  // S: K^T [d][j]; PV: P^T [j][i]
  alignas(16) __shared__ float Vs[64][68];   // [j][c]
  const int tid = threadIdx.x;
  const int tx = tid & 15;
  const int ty = tid >> 4;
  const int q0 = blockIdx.x * 64;
  const int h = blockIdx.y;
  const int b = blockIdx.z;
  const size_t base = (size_t)b * L_SZ * F_SZ + (size_t)h * D_SZ;

  const int li = tid >> 2;
  const int ld = (tid & 3) << 4;

  {
    const float* qp = QOb + base + (size_t)(q0 + li) * F_SZ + ld;
#pragma unroll
    for (int c = 0; c < 4; ++c) {
      const float4 v = *(const float4*)(qp + 4 * c);
      Qt[ld + 4 * c + 0][li] = v.x;
      Qt[ld + 4 * c + 1][li] = v.y;
      Qt[ld + 4 * c + 2][li] = v.z;
      Qt[ld + 4 * c + 3][li] = v.w;
    }
  }

  float mrow[4], lrow[4], acc[4][4];
#pragma unroll
  for (int a = 0; a < 4; ++a) {
    mrow[a] = -3.0e38f;
    lrow[a] = 0.f;
#pragma unroll
    for (int c = 0; c < 4; ++c) acc[a][c] = 0.f;
  }

  float4 kr[4], vr[4];
  {
    const float* kp = Kb + base + (size_t)li * F_SZ + ld;
    const float* vp = Vb + base + (size_t)li * F_SZ + ld;
#pragma unroll
    for (int c = 0; c < 4; ++c) {
      kr[c] = *(const float4*)(kp + 4 * c);
      vr[c] = *(const float4*)(vp + 4 * c);
    }
  }

  for (int kt = 0; kt < 16; ++kt) {
    const int k0 = kt * 64;
    __syncthreads();
#pragma unroll
    for (int c = 0; c < 4; ++c) {
      KPt[ld + 4 * c + 0][li] = kr[c].x;
      KPt[ld + 4 * c + 1][li] = kr[c].y;
      KPt[ld + 4 * c + 2][li] = kr[c].z;
      KPt[ld + 4 * c + 3][li] = kr[c].w;
      *(float4*)&Vs[li][ld + 4 * c] = vr[c];
    }
    __syncthreads();
    if (kt < 15) {
      const float* kp = Kb + base + (size_t)(k0 + 64 + li) * F_SZ + ld;
      const float* vp = Vb + base + (size_t)(k0 + 64 + li) * F_SZ + ld;
#pragma unroll
      for (int c = 0; c < 4; ++c) {
        kr[c] = *(const float4*)(kp + 4 * c);
        vr[c] = *(const float4*)(vp + 4 * c);
      }
    }
    float s[4][4];
#pragma unroll
    for (int a = 0; a < 4; ++a)
#pragma unroll
      for (int j = 0; j < 4; ++j) s[a][j] = 0.f;
#pragma unroll 8
    for (int d = 0; d < 64; ++d) {
      const float4 qv = *(const float4*)&Qt[d][ty * 4];
      const float4 kv = *(const float4*)&KPt[d][tx * 4];
      const float ar[4] = {qv.x, qv.y, qv.z, qv.w};
      const float br[4] = {kv.x, kv.y, kv.z, kv.w};
#pragma unroll
      for (int a = 0; a < 4; ++a)
#pragma unroll
        for (int j = 0; j < 4; ++j) s[a][j] = fmaf(ar[a], br[j], s[a][j]);
    }
    __syncthreads();

#pragma unroll
    for (int a = 0; a < 4; ++a) {
      const float4 mk =
          *(const float4*)(mask + (size_t)(q0 + ty * 4 + a) * L_SZ + k0 + tx * 4);
      s[a][0] = fmaf(s[a][0], 0.125f, mk.x);
      s[a][1] = fmaf(s[a][1], 0.125f, mk.y);
      s[a][2] = fmaf(s[a][2], 0.125f, mk.z);
      s[a][3] = fmaf(s[a][3], 0.125f, mk.w);
      float mx = fmaxf(fmaxf(s[a][0], s[a][1]), fmaxf(s[a][2], s[a][3]));
#pragma unroll
      for (int off = 1; off < 16; off <<= 1)
        mx = fmaxf(mx, __shfl_xor(mx, off, 64));
      const float mnew = fmaxf(mrow[a], mx);
      const float alpha = __expf(mrow[a] - mnew);
      mrow[a] = mnew;
      float rs = 0.f;
#pragma unroll
      for (int j = 0; j < 4; ++j) {
        s[a][j] = __expf(s[a][j] - mnew);
        rs += s[a][j];
      }
#pragma unroll
      for (int off = 1; off < 16; off <<= 1) rs += __shfl_xor(rs, off, 64);
      lrow[a] = lrow[a] * alpha + rs;
#pragma unroll
      for (int c = 0; c < 4; ++c) acc[a][c] *= alpha;
#pragma unroll
      for (int j = 0; j < 4; ++j) KPt[tx * 4 + j][ty * 4 + a] = s[a][j];
    }
    __syncthreads();

#pragma unroll 8
    for (int j = 0; j < 64; ++j) {
      const float4 pv = *(const float4*)&KPt[j][ty * 4];
      const float4 vv = *(const float4*)&Vs[j][tx * 4];
      const float pr[4] = {pv.x, pv.y, pv.z, pv.w};
      const float vc[4] = {vv.x, vv.y, vv.z, vv.w};
#pragma unroll
      for (int a = 0; a < 4; ++a)
#pragma unroll
        for (int c = 0; c < 4; ++c) acc[a][c] = fmaf(pr[a], vc[c], acc[a][c]);
    }
  }

#pragma unroll
  for (int a = 0; a < 4; ++a) {
    const float inv = 1.f / lrow[a];
    const size_t e = base + (size_t)(q0 + ty * 4 + a) * F_SZ + tx * 4;
    if constexpr (SPLIT) {
      ushort4 h4, l4;
      split1(acc[a][0] * inv, h4.x, l4.x);
      split1(acc[a][1] * inv, h4.y, l4.y);
      split1(acc[a][2] * inv, h4.z, l4.z);
      split1(acc[a][3] * inv, h4.w, l4.w);
      *(ushort4*)(AOhi + e) = h4;
      *(ushort4*)(AOlo + e) = l4;
    } else {
      *(float4*)(QOb + e) = make_float4(acc[a][0] * inv, acc[a][1] * inv,
                                        acc[a][2] * inv, acc[a][3] * inv);
    }
  }
}

// ---------------------------------------------------------------------------
extern "C" void kernel_launch(void* const* d_in, const int* in_sizes, int n_in,
                              void* d_out, int out_size, void* d_ws,
                              size_t ws_size, hipStream_t stream) {
  const float* kv = (const float*)d_in[0];
  const float* q = (const float*)d_in[1];
  const float* mask = (const float*)d_in[2];
  const float* Wq = (const float*)d_in[3];
  const float* Wk = (const float*)d_in[4];
  const float* Wv = (const float*)d_in[5];
  const float* Wo = (const float*)d_in[6];
  const float* lqs = (const float*)d_in[7];
  const float* lqb = (const float*)d_in[8];
  const float* lks = (const float*)d_in[9];
  const float* lkb = (const float*)d_in[10];
  const float* lvs = (const float*)d_in[11];
  const float* lvb = (const float*)d_in[12];
  float* out = (float*)d_out;

  const size_t MB = 1024 * 1024;
  float* Qb = (float*)d_ws;
  float* Kb = Qb + (size_t)M_SZ * F_SZ;
  float* Vb = Kb + (size_t)M_SZ * F_SZ;

  if (ws_size >= 144 * MB) {
    // fast path: bf16x3 MFMA projections
    unsigned short* kvh = (unsigned short*)((char*)d_ws + 96 * MB);
    unsigned short* kvl = kvh + (size_t)M_SZ * F_SZ;
    unsigned short* Whi = (unsigned short*)((char*)d_ws + 128 * MB);
    unsigned short* Wlo = (unsigned short*)((char*)d_ws + 136 * MB);
    unsigned short* qh = (unsigned short*)d_out;  // d_out as scratch until Wo GEMM
    unsigned short* ql = qh + (size_t)M_SZ * F_SZ;
    unsigned short* AOhi = kvh;  // kv splits dead after QKV GEMMs
    unsigned short* AOlo = kvl;

    split_w<<<dim3(32, 32, 4), 256, 0, stream>>>(Wq, Wk, Wv, Wo, Whi, Wlo);
    split_a<<<dim3((M_SZ * F_SZ) / 1024, 2), 256, 0, stream>>>(kv, q, kvh, kvl,
                                                               qh, ql);
    gemm_x3_qkv<<<dim3(F_SZ / 128, M_SZ / 128, 3), 256, 0, stream>>>(
        qh, ql, kvh, kvl, Whi, Wlo, Qb, Kb, Vb);
    ln_kernel<<<dim3(M_SZ, 3), 256, 0, stream>>>(Qb, Kb, Vb, lqs, lqb, lks, lkb,
                                                 lvs, lvb);
    attn_kernel<1><<<dim3(L_SZ / 64, H_SZ, B_SZ), 256, 0, stream>>>(
        Qb, Kb, Vb, mask, AOhi, AOlo);
    gemm_x3_one<<<dim3(F_SZ / 128, M_SZ / 128, 1), 256, 0, stream>>>(
        AOhi, AOlo, Whi + (size_t)3 * 1024 * 1024, Wlo + (size_t)3 * 1024 * 1024,
        out);
  } else {
    // fallback: round-1 fp32 path (96 MB ws)
    gemm_qkv<<<dim3(F_SZ / BN, M_SZ / BM, 3), 256, 0, stream>>>(
        q, kv, Wq, Wk, Wv, Qb, Kb, Vb);
    ln_kernel<<<dim3(M_SZ, 3), 256, 0, stream>>>(Qb, Kb, Vb, lqs, lqb, lks, lkb,
                                                 lvs, lvb);
    attn_kernel<0><<<dim3(L_SZ / 64, H_SZ, B_SZ), 256, 0, stream>>>(
        Qb, Kb, Vb, mask, nullptr, nullptr);
    gemm_one<<<dim3(F_SZ / BN, M_SZ / BM, 1), 256, 0, stream>>>(Qb, Wo, out);
  }
}

// Round 9
// 981.152 us; speedup vs baseline: 1.5190x; 1.3517x over previous
//
#include <hip/hip_runtime.h>
#include <cstdint>
#include <cstddef>

// Problem constants
#define B_SZ 8
#define L_SZ 1024
#define F_SZ 1024
#define H_SZ 16
#define D_SZ 64
#define M_SZ (B_SZ * L_SZ)  // 8192 rows

typedef __attribute__((ext_vector_type(8))) short bf16x8;
typedef __attribute__((ext_vector_type(4))) float f32x4;

// ---------------------------------------------------------------------------
// fp32 -> (hi, lo) bf16 split. hi = truncated top-16 bits (exact residual),
// lo = RNE-bf16 of (x - hi). x ~= hi + lo with ~2^-17 relative error.
// ---------------------------------------------------------------------------
__device__ __forceinline__ void split1(float x, unsigned short& h,
                                       unsigned short& l) {
  const unsigned xb = __float_as_uint(x);
  h = (unsigned short)(xb >> 16);
  const float lf = x - __uint_as_float(xb & 0xFFFF0000u);
  const unsigned lb = __float_as_uint(lf);
  l = (unsigned short)((lb + 0x7FFFu + ((lb >> 16) & 1u)) >> 16);
}

__device__ __forceinline__ void gld16(const void* g, void* l) {
  __builtin_amdgcn_global_load_lds(
      (const __attribute__((address_space(1))) void*)g,
      (__attribute__((address_space(3))) void*)l, 16, 0, 0);
}

#define MFMA16(a, b, c) __builtin_amdgcn_mfma_f32_16x16x32_bf16((a), (b), (c), 0, 0, 0)

// ---------------------------------------------------------------------------
// bf16x3 MFMA GEMM (proven in round 4): C = A @ B^T_storage, 128x128 tiles.
// ---------------------------------------------------------------------------
__device__ __forceinline__ void gemm_x3_body(const unsigned short* __restrict__ Ah,
                                             const unsigned short* __restrict__ Al,
                                             const unsigned short* __restrict__ Bh,
                                             const unsigned short* __restrict__ Bl,
                                             float* __restrict__ C) {
  __shared__ bf16x8 sT[4][512];  // Ahi, Alo, Bhi, Blo tiles, 8KB each
  const int tid = threadIdx.x;
  const int lane = tid & 63;
  const int wave = tid >> 6;
  const int wr = wave >> 1, wc = wave & 1;
  const int lg = lane >> 4, lr = lane & 15;
  const int bn = blockIdx.x * 128;
  const int bm = blockIdx.y * 128;

  const unsigned short* gsrc = (wave == 0) ? Ah
                               : (wave == 1) ? Al
                               : (wave == 2) ? Bh
                                             : Bl;
  const int rowbase = (wave < 2) ? bm : bn;
  bf16x8* tile = sT[wave];
  const unsigned short* gw = gsrc + (size_t)(rowbase + lane) * 1024;

  f32x4 acc[4][4];
#pragma unroll
  for (int i = 0; i < 4; ++i)
#pragma unroll
    for (int j = 0; j < 4; ++j) acc[i][j] = {0.f, 0.f, 0.f, 0.f};

  for (int k0 = 0; k0 < 1024; k0 += 32) {
    __syncthreads();
#pragma unroll
    for (int q = 0; q < 8; ++q) {
      const unsigned short* gp = gw + (size_t)(q & 1) * 64 * 1024 + (q >> 1) * 8 + k0;
      gld16(gp, &tile[q * 64]);
    }
    __syncthreads();

    bf16x8 ah[4], al[4], bh[4], bl[4];
#pragma unroll
    for (int i = 0; i < 4; ++i) {
      const int s = lg * 128 + wr * 64 + i * 16 + lr;
      ah[i] = sT[0][s];
      al[i] = sT[1][s];
    }
#pragma unroll
    for (int j = 0; j < 4; ++j) {
      const int s = lg * 128 + wc * 64 + j * 16 + lr;
      bh[j] = sT[2][s];
      bl[j] = sT[3][s];
    }
#pragma unroll
    for (int i = 0; i < 4; ++i)
#pragma unroll
      for (int j = 0; j < 4; ++j) {
        acc[i][j] = MFMA16(ah[i], bh[j], acc[i][j]);
        acc[i][j] = MFMA16(ah[i], bl[j], acc[i][j]);
        acc[i][j] = MFMA16(al[i], bh[j], acc[i][j]);
      }
  }

  // C/D layout: col = lane&15, row = (lane>>4)*4 + reg
  const int r0 = bm + wr * 64 + lg * 4;
  const int c0 = bn + wc * 64 + lr;
#pragma unroll
  for (int i = 0; i < 4; ++i)
#pragma unroll
    for (int j = 0; j < 4; ++j) {
      float* cp = C + (size_t)(r0 + i * 16) * 1024 + c0 + j * 16;
      cp[0] = acc[i][j][0];
      cp[1024] = acc[i][j][1];
      cp[2048] = acc[i][j][2];
      cp[3072] = acc[i][j][3];
    }
}

__global__ __launch_bounds__(256) void gemm_x3_qkv(
    const unsigned short* __restrict__ qh, const unsigned short* __restrict__ ql,
    const unsigned short* __restrict__ kvh, const unsigned short* __restrict__ kvl,
    const unsigned short* __restrict__ Whi, const unsigned short* __restrict__ Wlo,
    float* __restrict__ Qb, float* __restrict__ Kb, float* __restrict__ Vb) {
  const int z = blockIdx.z;
  const unsigned short* Ah = (z == 0) ? qh : kvh;
  const unsigned short* Al = (z == 0) ? ql : kvl;
  const unsigned short* Bh = Whi + (size_t)z * (1024 * 1024);
  const unsigned short* Bl = Wlo + (size_t)z * (1024 * 1024);
  float* C = (z == 0) ? Qb : (z == 1) ? Kb : Vb;
  gemm_x3_body(Ah, Al, Bh, Bl, C);
}

__global__ __launch_bounds__(256) void gemm_x3_one(
    const unsigned short* __restrict__ Ah, const unsigned short* __restrict__ Al,
    const unsigned short* __restrict__ Bh, const unsigned short* __restrict__ Bl,
    float* __restrict__ C) {
  gemm_x3_body(Ah, Al, Bh, Bl, C);
}

// ---------------------------------------------------------------------------
// Weight split + transpose (proven round 4).
// ---------------------------------------------------------------------------
__global__ __launch_bounds__(256) void split_w(
    const float* __restrict__ Wq, const float* __restrict__ Wk,
    const float* __restrict__ Wv, const float* __restrict__ Wo,
    unsigned short* __restrict__ Whi, unsigned short* __restrict__ Wlo) {
  const int z = blockIdx.z;
  const float* W = (z == 0) ? Wq : (z == 1) ? Wk : (z == 2) ? Wv : Wo;
  unsigned short* oh = Whi + (size_t)z * (1024 * 1024);
  unsigned short* ol = Wlo + (size_t)z * (1024 * 1024);
  __shared__ float t[32][33];
  const int k0 = blockIdx.y * 32, n0 = blockIdx.x * 32;
  const int tid = threadIdx.x;
  const int r = tid >> 3, c4 = (tid & 7) * 4;
  const float4 v = *(const float4*)&W[(size_t)(k0 + r) * 1024 + n0 + c4];
  t[r][c4 + 0] = v.x;
  t[r][c4 + 1] = v.y;
  t[r][c4 + 2] = v.z;
  t[r][c4 + 3] = v.w;
  __syncthreads();
  ushort4 h4, l4;
  split1(t[c4 + 0][r], h4.x, l4.x);
  split1(t[c4 + 1][r], h4.y, l4.y);
  split1(t[c4 + 2][r], h4.z, l4.z);
  split1(t[c4 + 3][r], h4.w, l4.w);
  const size_t o = (size_t)(n0 + r) * 1024 + k0 + c4;
  *(ushort4*)&oh[o] = h4;
  *(ushort4*)&ol[o] = l4;
}

// A-matrix split (proven round 4): z=0 kv, z=1 q
__global__ __launch_bounds__(256) void split_a(
    const float* __restrict__ kv, const float* __restrict__ q,
    unsigned short* __restrict__ kvh, unsigned short* __restrict__ kvl,
    unsigned short* __restrict__ qh, unsigned short* __restrict__ ql) {
  const int z = blockIdx.y;
  const float* src = (z == 0) ? kv : q;
  unsigned short* dh = (z == 0) ? kvh : qh;
  unsigned short* dl = (z == 0) ? kvl : ql;
  const size_t idx = (size_t)blockIdx.x * 256 + threadIdx.x;
  const float4 v = ((const float4*)src)[idx];
  ushort4 h4, l4;
  split1(v.x, h4.x, l4.x);
  split1(v.y, h4.y, l4.y);
  split1(v.z, h4.z, l4.z);
  split1(v.w, h4.w, l4.w);
  ((ushort4*)dh)[idx] = h4;
  ((ushort4*)dl)[idx] = l4;
}

// ---------------------------------------------------------------------------
// LayerNorm + output split. z=0: Q -> (Qh,Ql) bf16; z=1: K -> (Kh,Kl) bf16;
// z=2: V in-place f32 (transposed+split later by split_vt).
// ---------------------------------------------------------------------------
__global__ __launch_bounds__(256) void ln_split(
    const float* __restrict__ Qb, const float* __restrict__ Kb,
    float* __restrict__ Vb, const float* __restrict__ sq,
    const float* __restrict__ bq, const float* __restrict__ sk,
    const float* __restrict__ bk, const float* __restrict__ sv,
    const float* __restrict__ bv, unsigned short* __restrict__ Qh,
    unsigned short* __restrict__ Ql, unsigned short* __restrict__ Kh,
    unsigned short* __restrict__ Kl) {
  const int z = blockIdx.y;
  const float* buf = (z == 0) ? Qb : (z == 1) ? Kb : Vb;
  const float* sc = (z == 0) ? sq : (z == 1) ? sk : sv;
  const float* bi = (z == 0) ? bq : (z == 1) ? bk : bv;

  const float* row = buf + (size_t)blockIdx.x * F_SZ;
  const int tid = threadIdx.x;
  float4 v = *(const float4*)(row + tid * 4);
  float s = v.x + v.y + v.z + v.w;
  float ss = v.x * v.x + v.y * v.y + v.z * v.z + v.w * v.w;
#pragma unroll
  for (int off = 1; off < 64; off <<= 1) {
    s += __shfl_xor(s, off, 64);
    ss += __shfl_xor(ss, off, 64);
  }
  __shared__ float red[2][4];
  if ((tid & 63) == 0) {
    red[0][tid >> 6] = s;
    red[1][tid >> 6] = ss;
  }
  __syncthreads();
  s = red[0][0] + red[0][1] + red[0][2] + red[0][3];
  ss = red[1][0] + red[1][1] + red[1][2] + red[1][3];
  const float mu = s * (1.f / F_SZ);
  const float var = ss * (1.f / F_SZ) - mu * mu;
  const float r = rsqrtf(var + 1e-6f);
  const float4 scv = *(const float4*)(sc + tid * 4);
  const float4 biv = *(const float4*)(bi + tid * 4);
  v.x = (v.x - mu) * r * scv.x + biv.x;
  v.y = (v.y - mu) * r * scv.y + biv.y;
  v.z = (v.z - mu) * r * scv.z + biv.z;
  v.w = (v.w - mu) * r * scv.w + biv.w;
  if (z == 2) {
    *(float4*)((float*)row + tid * 4) = v;
  } else {
    unsigned short* dh = (z == 0) ? Qh : Kh;
    unsigned short* dl = (z == 0) ? Ql : Kl;
    ushort4 h4, l4;
    split1(v.x, h4.x, l4.x);
    split1(v.y, h4.y, l4.y);
    split1(v.z, h4.z, l4.z);
    split1(v.w, h4.w, l4.w);
    const size_t o = (size_t)blockIdx.x * F_SZ + tid * 4;
    *(ushort4*)(dh + o) = h4;
    *(ushort4*)(dl + o) = l4;
  }
}

// ---------------------------------------------------------------------------
// V transpose + split: Vb[b][l][h*64+d] f32 -> Vth/Vtl[(b*16+h)*64+d][l] bf16.
// Block = (ltile of 64, h, b), 64x64 tile through LDS.
// ---------------------------------------------------------------------------
__global__ __launch_bounds__(256) void split_vt(
    const float* __restrict__ Vb, unsigned short* __restrict__ Vth,
    unsigned short* __restrict__ Vtl) {
  __shared__ float t[64][68];
  const int l0 = blockIdx.x * 64;
  const int h = blockIdx.y, b = blockIdx.z;
  const int tid = threadIdx.x;
  const int r = tid >> 2, c0 = (tid & 3) * 16;
  const float* src = Vb + (size_t)(b * L_SZ + l0 + r) * F_SZ + h * D_SZ + c0;
#pragma unroll
  for (int c = 0; c < 4; ++c) {
    const float4 v = *(const float4*)(src + c * 4);
    t[r][c0 + c * 4 + 0] = v.x;
    t[r][c0 + c * 4 + 1] = v.y;
    t[r][c0 + c * 4 + 2] = v.z;
    t[r][c0 + c * 4 + 3] = v.w;
  }
  __syncthreads();
  const int d = tid >> 2, lc = (tid & 3) * 16;
  unsigned short* oh =
      Vth + ((size_t)(b * H_SZ + h) * D_SZ + d) * L_SZ + l0 + lc;
  unsigned short* ol =
      Vtl + ((size_t)(b * H_SZ + h) * D_SZ + d) * L_SZ + l0 + lc;
#pragma unroll
  for (int c = 0; c < 4; ++c) {
    ushort4 h4, l4;
    split1(t[lc + c * 4 + 0][d], h4.x, l4.x);
    split1(t[lc + c * 4 + 1][d], h4.y, l4.y);
    split1(t[lc + c * 4 + 2][d], h4.z, l4.z);
    split1(t[lc + c * 4 + 3][d], h4.w, l4.w);
    *(ushort4*)(oh + c * 4) = h4;
    *(ushort4*)(ol + c * 4) = l4;
  }
}

// ---------------------------------------------------------------------------
// MFMA flash attention, bf16x3. Block = (64 q-rows, head, batch), 4 waves,
// wave owns 16 q-rows. K/V tiles of 64 keys staged via global_load_lds in
// chunk-major A/B-fragment layout (slot = kchunk*64 + row, 16B slots).
// Q fragments held in registers; Q LDS region reused for per-wave P (hi/lo).
// Online softmax in fp32 on the C-fragment layout. Output written pre-split.
// ---------------------------------------------------------------------------
__global__ __launch_bounds__(256) void attn_mfma(
    const unsigned short* __restrict__ Qh, const unsigned short* __restrict__ Ql,
    const unsigned short* __restrict__ Kh, const unsigned short* __restrict__ Kl,
    const unsigned short* __restrict__ Vth, const unsigned short* __restrict__ Vtl,
    const float* __restrict__ mask, unsigned short* __restrict__ AOhi,
    unsigned short* __restrict__ AOlo) {
  __shared__ bf16x8 sQPh[512], sQPl[512];  // Q tiles, then per-wave P regions
  __shared__ bf16x8 sKh[512], sKl[512];
  __shared__ bf16x8 sVh[512], sVl[512];
  const int tid = threadIdx.x;
  const int lane = tid & 63, wave = tid >> 6;
  const int lg = lane >> 4, lr = lane & 15;
  const int q0 = blockIdx.x * 64;
  const int h = blockIdx.y, b = blockIdx.z;

  // ---- stage Q (wave0 -> hi, wave1 -> lo), 8 gld16 each: slot = kchunk*64+row
  if (wave < 2) {
    const unsigned short* src = ((wave == 0) ? Qh : Ql) +
                                (size_t)(b * L_SZ + q0 + lane) * F_SZ + h * D_SZ;
    bf16x8* dst = (wave == 0) ? sQPh : sQPl;
#pragma unroll
    for (int i = 0; i < 8; ++i) gld16(src + i * 8, &dst[i * 64]);
  }
  __syncthreads();
  bf16x8 qfh[2], qfl[2];  // A-fragments: row = wave*16+lr, kchunk = ks*4+lg
#pragma unroll
  for (int ks = 0; ks < 2; ++ks) {
    qfh[ks] = sQPh[(ks * 4 + lg) * 64 + wave * 16 + lr];
    qfl[ks] = sQPl[(ks * 4 + lg) * 64 + wave * 16 + lr];
  }
  __syncthreads();  // all Q reads done; region becomes P

  unsigned short* Ph = (unsigned short*)(sQPh + wave * 128);
  unsigned short* Pl = (unsigned short*)(sQPl + wave * 128);

  float mrow[4], lrow[4];
  f32x4 o[4];
#pragma unroll
  for (int r = 0; r < 4; ++r) {
    mrow[r] = -3.0e38f;
    lrow[r] = 0.f;
  }
#pragma unroll
  for (int j = 0; j < 4; ++j) o[j] = {0.f, 0.f, 0.f, 0.f};

  for (int kt = 0; kt < 16; ++kt) {
    const int k0 = kt * 64;
    __syncthreads();  // prev tile's K/V/P reads complete
    {                 // wave w stages one of {Kh,Kl,Vth,Vtl}
      const unsigned short* src;
      bf16x8* dst;
      if (wave == 0) {
        src = Kh + (size_t)(b * L_SZ + k0 + lane) * F_SZ + h * D_SZ;
        dst = sKh;
      } else if (wave == 1) {
        src = Kl + (size_t)(b * L_SZ + k0 + lane) * F_SZ + h * D_SZ;
        dst = sKl;
      } else if (wave == 2) {
        src = Vth + ((size_t)(b * H_SZ + h) * D_SZ + lane) * L_SZ + k0;
        dst = sVh;
      } else {
        src = Vtl + ((size_t)(b * H_SZ + h) * D_SZ + lane) * L_SZ + k0;
        dst = sVl;
      }
#pragma unroll
      for (int i = 0; i < 8; ++i) gld16(src + i * 8, &dst[i * 64]);
    }
    __syncthreads();  // vmcnt drained by compiler before barrier

    // ---- S = Q K^T (x3), 4 col-fragments of 16 keys
    f32x4 s[4];
#pragma unroll
    for (int j = 0; j < 4; ++j) s[j] = {0.f, 0.f, 0.f, 0.f};
#pragma unroll
    for (int ks = 0; ks < 2; ++ks)
#pragma unroll
      for (int j = 0; j < 4; ++j) {
        const bf16x8 kfh = sKh[(ks * 4 + lg) * 64 + j * 16 + lr];
        const bf16x8 kfl = sKl[(ks * 4 + lg) * 64 + j * 16 + lr];
        s[j] = MFMA16(qfh[ks], kfh, s[j]);
        s[j] = MFMA16(qfh[ks], kfl, s[j]);
        s[j] = MFMA16(qfl[ks], kfh, s[j]);
      }

    // ---- online softmax (fp32) + P -> LDS (hi/lo, A-fragment layout)
#pragma unroll
    for (int r = 0; r < 4; ++r) {
      const float* mp =
          mask + (size_t)(q0 + wave * 16 + lg * 4 + r) * L_SZ + k0;
      float sc[4];
#pragma unroll
      for (int j = 0; j < 4; ++j) sc[j] = s[j][r] * 0.125f + mp[j * 16 + lr];
      float mx = fmaxf(fmaxf(sc[0], sc[1]), fmaxf(sc[2], sc[3]));
#pragma unroll
      for (int off = 1; off < 16; off <<= 1)
        mx = fmaxf(mx, __shfl_xor(mx, off, 64));
      const float mnew = fmaxf(mrow[r], mx);
      const float alpha = __expf(mrow[r] - mnew);
      mrow[r] = mnew;
      float rs = 0.f;
#pragma unroll
      for (int j = 0; j < 4; ++j) {
        sc[j] = __expf(sc[j] - mnew);
        rs += sc[j];
      }
#pragma unroll
      for (int off = 1; off < 16; off <<= 1) rs += __shfl_xor(rs, off, 64);
      lrow[r] = lrow[r] * alpha + rs;
#pragma unroll
      for (int j = 0; j < 4; ++j) o[j][r] *= alpha;
#pragma unroll
      for (int j = 0; j < 4; ++j) {
        const int key = j * 16 + lr;       // C layout: col = lane&15
        const int row = lg * 4 + r;        // row = (lane>>4)*4 + reg
        const int idx = (key >> 3) * 128 + row * 8 + (key & 7);
        unsigned short hh, ll;
        split1(sc[j], hh, ll);
        Ph[idx] = hh;
        Pl[idx] = ll;
      }
    }

    // ---- O += P V (x3); A = P (rows=q, k=keys), B = Vt (rows=d, k=keys)
#pragma unroll
    for (int ks = 0; ks < 2; ++ks) {
      const bf16x8 pfh = ((bf16x8*)Ph)[(ks * 4 + lg) * 16 + lr];
      const bf16x8 pfl = ((bf16x8*)Pl)[(ks * 4 + lg) * 16 + lr];
#pragma unroll
      for (int j = 0; j < 4; ++j) {
        const bf16x8 vfh = sVh[(ks * 4 + lg) * 64 + j * 16 + lr];
        const bf16x8 vfl = sVl[(ks * 4 + lg) * 64 + j * 16 + lr];
        o[j] = MFMA16(pfh, vfh, o[j]);
        o[j] = MFMA16(pfh, vfl, o[j]);
        o[j] = MFMA16(pfl, vfh, o[j]);
      }
    }
  }

  // ---- epilogue: normalize, split, store
#pragma unroll
  for (int j = 0; j < 4; ++j)
#pragma unroll
    for (int r = 0; r < 4; ++r) {
      const int row = q0 + wave * 16 + lg * 4 + r;
      const int d = j * 16 + lr;
      const float val = o[j][r] / lrow[r];
      unsigned short hh, ll;
      split1(val, hh, ll);
      const size_t e = (size_t)(b * L_SZ + row) * F_SZ + h * D_SZ + d;
      AOhi[e] = hh;
      AOlo[e] = ll;
    }
}

// ---------------------------------------------------------------------------
// fp32 GEMM + fp32 attention + f32 LN (round-1 fallback path, ws < 144MB)
// ---------------------------------------------------------------------------
#define BM 128
#define BN 128
#define BK 8

__device__ __forceinline__ void gemm_body(const float* __restrict__ A,
                                          const float* __restrict__ W,
                                          float* __restrict__ C) {
  alignas(16) __shared__ float As[BK][BM + 4];
  alignas(16) __shared__ float Bs[BK][BN + 4];
  const int tid = threadIdx.x;
  const int tx = tid & 15;
  const int ty = tid >> 4;
  const int bn = blockIdx.x * BN;
  const int bm = blockIdx.y * BM;

  const int a_m = tid >> 1;
  const int a_k = (tid & 1) << 2;
  const int b_k = tid >> 5;
  const int b_n = (tid & 31) << 2;

  const float* Ap = A + (size_t)(bm + a_m) * F_SZ + a_k;
  const float* Wp = W + (size_t)b_k * F_SZ + bn + b_n;

  float acc[8][8];
#pragma unroll
  for (int i = 0; i < 8; ++i)
#pragma unroll
    for (int j = 0; j < 8; ++j) acc[i][j] = 0.f;

  float4 av = *(const float4*)Ap;
  float4 bv = *(const float4*)Wp;

  for (int k0 = 0; k0 < F_SZ; k0 += BK) {
    __syncthreads();
    As[a_k + 0][a_m] = av.x;
    As[a_k + 1][a_m] = av.y;
    As[a_k + 2][a_m] = av.z;
    As[a_k + 3][a_m] = av.w;
    *(float4*)&Bs[b_k][b_n] = bv;
    __syncthreads();
    if (k0 + BK < F_SZ) {
      av = *(const float4*)(Ap + k0 + BK);
      bv = *(const float4*)(Wp + (size_t)(k0 + BK) * F_SZ);
    }
#pragma unroll
    for (int k = 0; k < BK; ++k) {
      const float4 a0 = *(const float4*)&As[k][ty * 8];
      const float4 a1 = *(const float4*)&As[k][ty * 8 + 4];
      const float4 b0 = *(const float4*)&Bs[k][tx * 8];
      const float4 b1 = *(const float4*)&Bs[k][tx * 8 + 4];
      const float ar[8] = {a0.x, a0.y, a0.z, a0.w, a1.x, a1.y, a1.z, a1.w};
      const float br[8] = {b0.x, b0.y, b0.z, b0.w, b1.x, b1.y, b1.z, b1.w};
#pragma unroll
      for (int i = 0; i < 8; ++i)
#pragma unroll
        for (int j = 0; j < 8; ++j)
          acc[i][j] = fmaf(ar[i], br[j], acc[i][j]);
    }
  }

#pragma unroll
  for (int i = 0; i < 8; ++i) {
    float* crow = C + (size_t)(bm + ty * 8 + i) * F_SZ + bn + tx * 8;
    *(float4*)crow = make_float4(acc[i][0], acc[i][1], acc[i][2], acc[i][3]);
    *(float4*)(crow + 4) = make_float4(acc[i][4], acc[i][5], acc[i][6], acc[i][7]);
  }
}

__global__ __launch_bounds__(256) void gemm_qkv(
    const float* __restrict__ q, const float* __restrict__ kv,
    const float* __restrict__ Wq, const float* __restrict__ Wk,
    const float* __restrict__ Wv, float* __restrict__ Qb,
    float* __restrict__ Kb, float* __restrict__ Vb) {
  const int z = blockIdx.z;
  const float* A = (z == 0) ? q : kv;
  const float* W = (z == 0) ? Wq : (z == 1) ? Wk : Wv;
  float* C = (z == 0) ? Qb : (z == 1) ? Kb : Vb;
  gemm_body(A, W, C);
}

__global__ __launch_bounds__(256) void gemm_one(const float* __restrict__ A,
                                                const float* __restrict__ W,
                                                float* __restrict__ C) {
  gemm_body(A, W, C);
}

__global__ __launch_bounds__(256) void ln_kernel(
    float* __restrict__ Qb, float* __restrict__ Kb, float* __restrict__ Vb,
    const float* __restrict__ sq, const float* __restrict__ bq,
    const float* __restrict__ sk, const float* __restrict__ bk,
    const float* __restrict__ sv, const float* __restrict__ bv) {
  const int z = blockIdx.y;
  float* buf = (z == 0) ? Qb : (z == 1) ? Kb : Vb;
  const float* sc = (z == 0) ? sq : (z == 1) ? sk : sv;
  const float* bi = (z == 0) ? bq : (z == 1) ? bk : bv;

  float* row = buf + (size_t)blockIdx.x * F_SZ;
  const int tid = threadIdx.x;
  float4 v = *(const float4*)(row + tid * 4);
  float s = v.x + v.y + v.z + v.w;
  float ss = v.x * v.x + v.y * v.y + v.z * v.z + v.w * v.w;
#pragma unroll
  for (int off = 1; off < 64; off <<= 1) {
    s += __shfl_xor(s, off, 64);
    ss += __shfl_xor(ss, off, 64);
  }
  __shared__ float red[2][4];
  if ((tid & 63) == 0) {
    red[0][tid >> 6] = s;
    red[1][tid >> 6] = ss;
  }
  __syncthreads();
  s = red[0][0] + red[0][1] + red[0][2] + red[0][3];
  ss = red[1][0] + red[1][1] + red[1][2] + red[1][3];
  const float mu = s * (1.f / F_SZ);
  const float var = ss * (1.f / F_SZ) - mu * mu;
  const float r = rsqrtf(var + 1e-6f);
  const float4 scv = *(const float4*)(sc + tid * 4);
  const float4 biv = *(const float4*)(bi + tid * 4);
  v.x = (v.x - mu) * r * scv.x + biv.x;
  v.y = (v.y - mu) * r * scv.y + biv.y;
  v.z = (v.z - mu) * r * scv.z + biv.z;
  v.w = (v.w - mu) * r * scv.w + biv.w;
  *(float4*)(row + tid * 4) = v;
}

__global__ __launch_bounds__(256) void attn_kernel(
    float* __restrict__ QOb, const float* __restrict__ Kb,
    const float* __restrict__ Vb, const float* __restrict__ mask) {
  alignas(16) __shared__ float Qt[64][68];
  alignas(16) __shared__ float KPt[64][68];
  alignas(16) __shared__ float Vs[64][68];
  const int tid = threadIdx.x;
  const int tx = tid & 15;
  const int ty = tid >> 4;
  const int q0 = blockIdx.x * 64;
  const int h = blockIdx.y;
  const int b = blockIdx.z;
  const size_t base = (size_t)b * L_SZ * F_SZ + (size_t)h * D_SZ;

  const int li = tid >> 2;
  const int ld = (tid & 3) << 4;

  {
    const float* qp = QOb + base + (size_t)(q0 + li) * F_SZ + ld;
#pragma unroll
    for (int c = 0; c < 4; ++c) {
      const float4 v = *(const float4*)(qp + 4 * c);
      Qt[ld + 4 * c + 0][li] = v.x;
      Qt[ld + 4 * c + 1][li] = v.y;
      Qt[ld + 4 * c + 2][li] = v.z;
      Qt[ld + 4 * c + 3][li] = v.w;
    }
  }

  float mrow[4], lrow[4], acc[4][4];
#pragma unroll
  for (int a = 0; a < 4; ++a) {
    mrow[a] = -3.0e38f;
    lrow[a] = 0.f;
#pragma unroll
    for (int c = 0; c < 4; ++c) acc[a][c] = 0.f;
  }

  float4 kr[4], vr[4];
  {
    const float* kp = Kb + base + (size_t)li * F_SZ + ld;
    const float* vp = Vb + base + (size_t)li * F_SZ + ld;
#pragma unroll
    for (int c = 0; c < 4; ++c) {
      kr[c] = *(const float4*)(kp + 4 * c);
      vr[c] = *(const float4*)(vp + 4 * c);
    }
  }

  for (int kt = 0; kt < 16; ++kt) {
    const int k0 = kt * 64;
    __syncthreads();
#pragma unroll
    for (int c = 0; c < 4; ++c) {
      KPt[ld + 4 * c + 0][li] = kr[c].x;
      KPt[ld + 4 * c + 1][li] = kr[c].y;
      KPt[ld + 4 * c + 2][li] = kr[c].z;
      KPt[ld + 4 * c + 3][li] = kr[c].w;
      *(float4*)&Vs[li][ld + 4 * c] = vr[c];
    }
    __syncthreads();
    if (kt < 15) {
      const float* kp = Kb + base + (size_t)(k0 + 64 + li) * F_SZ + ld;
      const float* vp = Vb + base + (size_t)(k0 + 64 + li) * F_SZ + ld;
#pragma unroll
      for (int c = 0; c < 4; ++c) {
        kr[c] = *(const float4*)(kp + 4 * c);
        vr[c] = *(const float4*)(vp + 4 * c);
      }
    }
    float s[4][4];
#pragma unroll
    for (int a = 0; a < 4; ++a)
#pragma unroll
      for (int j = 0; j < 4; ++j) s[a][j] = 0.f;
#pragma unroll 8
    for (int d = 0; d < 64; ++d) {
      const float4 qv = *(const float4*)&Qt[d][ty * 4];
      const float4 kv = *(const float4*)&KPt[d][tx * 4];
      const float ar[4] = {qv.x, qv.y, qv.z, qv.w};
      const float br[4] = {kv.x, kv.y, kv.z, kv.w};
#pragma unroll
      for (int a = 0; a < 4; ++a)
#pragma unroll
        for (int j = 0; j < 4; ++j) s[a][j] = fmaf(ar[a], br[j], s[a][j]);
    }
    __syncthreads();

#pragma unroll
    for (int a = 0; a < 4; ++a) {
      const float4 mk =
          *(const float4*)(mask + (size_t)(q0 + ty * 4 + a) * L_SZ + k0 + tx * 4);
      s[a][0] = fmaf(s[a][0], 0.125f, mk.x);
      s[a][1] = fmaf(s[a][1], 0.125f, mk.y);
      s[a][2] = fmaf(s[a][2], 0.125f, mk.z);
      s[a][3] = fmaf(s[a][3], 0.125f, mk.w);
      float mx = fmaxf(fmaxf(s[a][0], s[a][1]), fmaxf(s[a][2], s[a][3]));
#pragma unroll
      for (int off = 1; off < 16; off <<= 1)
        mx = fmaxf(mx, __shfl_xor(mx, off, 64));
      const float mnew = fmaxf(mrow[a], mx);
      const float alpha = __expf(mrow[a] - mnew);
      mrow[a] = mnew;
      float rs = 0.f;
#pragma unroll
      for (int j = 0; j < 4; ++j) {
        s[a][j] = __expf(s[a][j] - mnew);
        rs += s[a][j];
      }
#pragma unroll
      for (int off = 1; off < 16; off <<= 1) rs += __shfl_xor(rs, off, 64);
      lrow[a] = lrow[a] * alpha + rs;
#pragma unroll
      for (int c = 0; c < 4; ++c) acc[a][c] *= alpha;
#pragma unroll
      for (int j = 0; j < 4; ++j) KPt[tx * 4 + j][ty * 4 + a] = s[a][j];
    }
    __syncthreads();

#pragma unroll 8
    for (int j = 0; j < 64; ++j) {
      const float4 pv = *(const float4*)&KPt[j][ty * 4];
      const float4 vv = *(const float4*)&Vs[j][tx * 4];
      const float pr[4] = {pv.x, pv.y, pv.z, pv.w};
      const float vc[4] = {vv.x, vv.y, vv.z, vv.w};
#pragma unroll
      for (int a = 0; a < 4; ++a)
#pragma unroll
        for (int c = 0; c < 4; ++c) acc[a][c] = fmaf(pr[a], vc[c], acc[a][c]);
    }
  }

#pragma unroll
  for (int a = 0; a < 4; ++a) {
    const float inv = 1.f / lrow[a];
    *(float4*)(QOb + base + (size_t)(q0 + ty * 4 + a) * F_SZ + tx * 4) =
        make_float4(acc[a][0] * inv, acc[a][1] * inv, acc[a][2] * inv,
                    acc[a][3] * inv);
  }
}

// ---------------------------------------------------------------------------
extern "C" void kernel_launch(void* const* d_in, const int* in_sizes, int n_in,
                              void* d_out, int out_size, void* d_ws,
                              size_t ws_size, hipStream_t stream) {
  const float* kv = (const float*)d_in[0];
  const float* q = (const float*)d_in[1];
  const float* mask = (const float*)d_in[2];
  const float* Wq = (const float*)d_in[3];
  const float* Wk = (const float*)d_in[4];
  const float* Wv = (const float*)d_in[5];
  const float* Wo = (const float*)d_in[6];
  const float* lqs = (const float*)d_in[7];
  const float* lqb = (const float*)d_in[8];
  const float* lks = (const float*)d_in[9];
  const float* lkb = (const float*)d_in[10];
  const float* lvs = (const float*)d_in[11];
  const float* lvb = (const float*)d_in[12];
  float* out = (float*)d_out;

  const size_t MB = 1024 * 1024;
  float* Qb = (float*)d_ws;                       // [0,32) MB
  float* Kb = Qb + (size_t)M_SZ * F_SZ;           // [32,64)
  float* Vb = Kb + (size_t)M_SZ * F_SZ;           // [64,96)

  if (ws_size >= 144 * MB) {
    // region D [96,128): QKV-GEMM inputs kvh/kvl, then Qh/Ql after LN
    unsigned short* kvh = (unsigned short*)((char*)d_ws + 96 * MB);
    unsigned short* kvl = kvh + (size_t)M_SZ * F_SZ;
    // region E [128,144): weight splits (persistent)
    unsigned short* Whi = (unsigned short*)((char*)d_ws + 128 * MB);
    unsigned short* Wlo = (unsigned short*)((char*)d_ws + 136 * MB);
    // d_out: qh/ql for QKV GEMM, then Kh/Kl after LN, then final output
    unsigned short* qh = (unsigned short*)d_out;
    unsigned short* ql = qh + (size_t)M_SZ * F_SZ;
    unsigned short* Qhs = kvh;                     // [96,112): Q hi (post-LN)
    unsigned short* Qls = kvl;                     // [112,128): Q lo
    unsigned short* Khs = (unsigned short*)d_out;  // Kh over dead qh
    unsigned short* Kls = Khs + (size_t)M_SZ * F_SZ;
    unsigned short* Vth = (unsigned short*)d_ws;   // [0,16): over dead Qb f32
    unsigned short* Vtl = Vth + (size_t)M_SZ * F_SZ;  // [16,32)
    unsigned short* AOhi = (unsigned short*)Kb;    // [32,48): over dead Kb f32
    unsigned short* AOlo = AOhi + (size_t)M_SZ * F_SZ;  // [48,64)

    split_w<<<dim3(32, 32, 4), 256, 0, stream>>>(Wq, Wk, Wv, Wo, Whi, Wlo);
    split_a<<<dim3((M_SZ * F_SZ) / 1024, 2), 256, 0, stream>>>(kv, q, kvh, kvl,
                                                               qh, ql);
    gemm_x3_qkv<<<dim3(F_SZ / 128, M_SZ / 128, 3), 256, 0, stream>>>(
        qh, ql, kvh, kvl, Whi, Wlo, Qb, Kb, Vb);
    // LN: z=0 Qb -> Qhs/Qls, z=1 Kb -> Khs/Kls (d_out), z=2 Vb in place
    ln_split<<<dim3(M_SZ, 3), 256, 0, stream>>>(Qb, Kb, Vb, lqs, lqb, lks, lkb,
                                                lvs, lvb, Qhs, Qls, Khs, Kls);
    // V transpose+split into [0,32) (Qb f32 dead after ln_split)
    split_vt<<<dim3(L_SZ / 64, H_SZ, B_SZ), 256, 0, stream>>>(Vb, Vth, Vtl);
    // MFMA attention -> AO hi/lo into [32,64) (Kb f32 dead)
    attn_mfma<<<dim3(L_SZ / 64, H_SZ, B_SZ), 256, 0, stream>>>(
        Qhs, Qls, Khs, Kls, Vth, Vtl, mask, AOhi, AOlo);
    // output projection (overwrites dead Kh/Kl in d_out)
    gemm_x3_one<<<dim3(F_SZ / 128, M_SZ / 128, 1), 256, 0, stream>>>(
        AOhi, AOlo, Whi + (size_t)3 * 1024 * 1024, Wlo + (size_t)3 * 1024 * 1024,
        out);
  } else {
    // fallback: round-1 fp32 path (96 MB ws)
    gemm_qkv<<<dim3(F_SZ / BN, M_SZ / BM, 3), 256, 0, stream>>>(
        q, kv, Wq, Wk, Wv, Qb, Kb, Vb);
    ln_kernel<<<dim3(M_SZ, 3), 256, 0, stream>>>(Qb, Kb, Vb, lqs, lqb, lks, lkb,
                                                 lvs, lvb);
    attn_kernel<<<dim3(L_SZ / 64, H_SZ, B_SZ), 256, 0, stream>>>(Qb, Kb, Vb,
                                                                 mask);
    gemm_one<<<dim3(F_SZ / BN, M_SZ / BM, 1), 256, 0, stream>>>(Qb, Wo, out);
  }
}

// Round 10
// 979.340 us; speedup vs baseline: 1.5218x; 1.0018x over previous
//
#include <hip/hip_runtime.h>
#include <cstdint>
#include <cstddef>

// Problem constants
#define B_SZ 8
#define L_SZ 1024
#define F_SZ 1024
#define H_SZ 16
#define D_SZ 64
#define M_SZ (B_SZ * L_SZ)  // 8192 rows

typedef __attribute__((ext_vector_type(8))) short bf16x8;
typedef __attribute__((ext_vector_type(4))) float f32x4;

// ---------------------------------------------------------------------------
// fp32 -> (hi, lo) bf16 split. hi = truncated top-16 bits (exact residual),
// lo = RNE-bf16 of (x - hi). x ~= hi + lo with ~2^-17 relative error.
// ---------------------------------------------------------------------------
__device__ __forceinline__ void split1(float x, unsigned short& h,
                                       unsigned short& l) {
  const unsigned xb = __float_as_uint(x);
  h = (unsigned short)(xb >> 16);
  const float lf = x - __uint_as_float(xb & 0xFFFF0000u);
  const unsigned lb = __float_as_uint(lf);
  l = (unsigned short)((lb + 0x7FFFu + ((lb >> 16) & 1u)) >> 16);
}

__device__ __forceinline__ void gld16(const void* g, void* l) {
  __builtin_amdgcn_global_load_lds(
      (const __attribute__((address_space(1))) void*)g,
      (__attribute__((address_space(3))) void*)l, 16, 0, 0);
}

#define MFMA16(a, b, c) __builtin_amdgcn_mfma_f32_16x16x32_bf16((a), (b), (c), 0, 0, 0)

// ---------------------------------------------------------------------------
// bf16x3 MFMA GEMM, double-buffered: C = A @ B^T_storage, 128x128 tiles.
// R9 change: LDS 2x32KB dbuf; per K-step {ds_read frags(cur) -> issue
// prefetch(cur^1, k+1) -> 48 MFMA -> one __syncthreads()}. The barrier's
// vmcnt(0) drain now waits on loads that aged through the whole compute
// phase instead of freshly-issued ones (R9 counters: MfmaUtil 14.8%,
// VALUBusy 14.5% -> latency-bound on the stage-then-drain structure).
// ds_reads precede the prefetch issue so alias-conservative codegen cannot
// insert a vmcnt wait ahead of them.
// ---------------------------------------------------------------------------
__device__ __forceinline__ void stage_tile(const unsigned short* gw,
                                           bf16x8* dst, int k0) {
#pragma unroll
  for (int q = 0; q < 8; ++q) {
    // instr q: lanes cover rows (q&1)*64+lane, k-chunk q>>1 (8 bf16 = 16B)
    const unsigned short* gp =
        gw + (size_t)(q & 1) * 64 * 1024 + (q >> 1) * 8 + k0;
    gld16(gp, &dst[q * 64]);
  }
}

__device__ __forceinline__ void gemm_x3_body(const unsigned short* __restrict__ Ah,
                                             const unsigned short* __restrict__ Al,
                                             const unsigned short* __restrict__ Bh,
                                             const unsigned short* __restrict__ Bl,
                                             float* __restrict__ C) {
  __shared__ bf16x8 sT[2][4][512];  // dbuf x {Ahi, Alo, Bhi, Blo} x 8KB
  const int tid = threadIdx.x;
  const int lane = tid & 63;
  const int wave = tid >> 6;
  const int wr = wave >> 1, wc = wave & 1;
  const int lg = lane >> 4, lr = lane & 15;
  const int bn = blockIdx.x * 128;
  const int bm = blockIdx.y * 128;

  // staging: wave w owns tile w (0:Ahi 1:Alo 2:Bhi 3:Blo)
  const unsigned short* gsrc = (wave == 0) ? Ah
                               : (wave == 1) ? Al
                               : (wave == 2) ? Bh
                                             : Bl;
  const int rowbase = (wave < 2) ? bm : bn;
  const unsigned short* gw = gsrc + (size_t)(rowbase + lane) * 1024;

  f32x4 acc[4][4];
#pragma unroll
  for (int i = 0; i < 4; ++i)
#pragma unroll
    for (int j = 0; j < 4; ++j) acc[i][j] = {0.f, 0.f, 0.f, 0.f};

  // prologue: stage tile 0 into buf 0 and drain
  stage_tile(gw, sT[0][wave], 0);
  __syncthreads();

  for (int kt = 0; kt < 32; ++kt) {
    const int cur = kt & 1;

    // fragment reads from the landed buffer (placed before the prefetch
    // issue so no conservative vmcnt wait can precede them)
    bf16x8 ah[4], al[4], bh[4], bl[4];
#pragma unroll
    for (int i = 0; i < 4; ++i) {
      const int s = lg * 128 + wr * 64 + i * 16 + lr;
      ah[i] = sT[cur][0][s];
      al[i] = sT[cur][1][s];
    }
#pragma unroll
    for (int j = 0; j < 4; ++j) {
      const int s = lg * 128 + wc * 64 + j * 16 + lr;
      bh[j] = sT[cur][2][s];
      bl[j] = sT[cur][3][s];
    }

    // prefetch next K-tile into the other buffer; lands during MFMA phase
    if (kt < 31) stage_tile(gw, sT[cur ^ 1][wave], (kt + 1) * 32);

#pragma unroll
    for (int i = 0; i < 4; ++i)
#pragma unroll
      for (int j = 0; j < 4; ++j) {
        acc[i][j] = MFMA16(ah[i], bh[j], acc[i][j]);
        acc[i][j] = MFMA16(ah[i], bl[j], acc[i][j]);
        acc[i][j] = MFMA16(al[i], bh[j], acc[i][j]);
      }

    // one barrier per K-step: drains the aged prefetch, protects buf reuse
    __syncthreads();
  }

  // C/D layout: col = lane&15, row = (lane>>4)*4 + reg
  const int r0 = bm + wr * 64 + lg * 4;
  const int c0 = bn + wc * 64 + lr;
#pragma unroll
  for (int i = 0; i < 4; ++i)
#pragma unroll
    for (int j = 0; j < 4; ++j) {
      float* cp = C + (size_t)(r0 + i * 16) * 1024 + c0 + j * 16;
      cp[0] = acc[i][j][0];
      cp[1024] = acc[i][j][1];
      cp[2048] = acc[i][j][2];
      cp[3072] = acc[i][j][3];
    }
}

__global__ __launch_bounds__(256) void gemm_x3_qkv(
    const unsigned short* __restrict__ qh, const unsigned short* __restrict__ ql,
    const unsigned short* __restrict__ kvh, const unsigned short* __restrict__ kvl,
    const unsigned short* __restrict__ Whi, const unsigned short* __restrict__ Wlo,
    float* __restrict__ Qb, float* __restrict__ Kb, float* __restrict__ Vb) {
  const int z = blockIdx.z;
  const unsigned short* Ah = (z == 0) ? qh : kvh;
  const unsigned short* Al = (z == 0) ? ql : kvl;
  const unsigned short* Bh = Whi + (size_t)z * (1024 * 1024);
  const unsigned short* Bl = Wlo + (size_t)z * (1024 * 1024);
  float* C = (z == 0) ? Qb : (z == 1) ? Kb : Vb;
  gemm_x3_body(Ah, Al, Bh, Bl, C);
}

__global__ __launch_bounds__(256) void gemm_x3_one(
    const unsigned short* __restrict__ Ah, const unsigned short* __restrict__ Al,
    const unsigned short* __restrict__ Bh, const unsigned short* __restrict__ Bl,
    float* __restrict__ C) {
  gemm_x3_body(Ah, Al, Bh, Bl, C);
}

// ---------------------------------------------------------------------------
// Weight split + transpose (proven round 4).
// ---------------------------------------------------------------------------
__global__ __launch_bounds__(256) void split_w(
    const float* __restrict__ Wq, const float* __restrict__ Wk,
    const float* __restrict__ Wv, const float* __restrict__ Wo,
    unsigned short* __restrict__ Whi, unsigned short* __restrict__ Wlo) {
  const int z = blockIdx.z;
  const float* W = (z == 0) ? Wq : (z == 1) ? Wk : (z == 2) ? Wv : Wo;
  unsigned short* oh = Whi + (size_t)z * (1024 * 1024);
  unsigned short* ol = Wlo + (size_t)z * (1024 * 1024);
  __shared__ float t[32][33];
  const int k0 = blockIdx.y * 32, n0 = blockIdx.x * 32;
  const int tid = threadIdx.x;
  const int r = tid >> 3, c4 = (tid & 7) * 4;
  const float4 v = *(const float4*)&W[(size_t)(k0 + r) * 1024 + n0 + c4];
  t[r][c4 + 0] = v.x;
  t[r][c4 + 1] = v.y;
  t[r][c4 + 2] = v.z;
  t[r][c4 + 3] = v.w;
  __syncthreads();
  ushort4 h4, l4;
  split1(t[c4 + 0][r], h4.x, l4.x);
  split1(t[c4 + 1][r], h4.y, l4.y);
  split1(t[c4 + 2][r], h4.z, l4.z);
  split1(t[c4 + 3][r], h4.w, l4.w);
  const size_t o = (size_t)(n0 + r) * 1024 + k0 + c4;
  *(ushort4*)&oh[o] = h4;
  *(ushort4*)&ol[o] = l4;
}

// A-matrix split (proven round 4): z=0 kv, z=1 q
__global__ __launch_bounds__(256) void split_a(
    const float* __restrict__ kv, const float* __restrict__ q,
    unsigned short* __restrict__ kvh, unsigned short* __restrict__ kvl,
    unsigned short* __restrict__ qh, unsigned short* __restrict__ ql) {
  const int z = blockIdx.y;
  const float* src = (z == 0) ? kv : q;
  unsigned short* dh = (z == 0) ? kvh : qh;
  unsigned short* dl = (z == 0) ? kvl : ql;
  const size_t idx = (size_t)blockIdx.x * 256 + threadIdx.x;
  const float4 v = ((const float4*)src)[idx];
  ushort4 h4, l4;
  split1(v.x, h4.x, l4.x);
  split1(v.y, h4.y, l4.y);
  split1(v.z, h4.z, l4.z);
  split1(v.w, h4.w, l4.w);
  ((ushort4*)dh)[idx] = h4;
  ((ushort4*)dl)[idx] = l4;
}

// ---------------------------------------------------------------------------
// LayerNorm + output split. z=0: Q -> (Qh,Ql) bf16; z=1: K -> (Kh,Kl) bf16;
// z=2: V in-place f32 (transposed+split later by split_vt).
// ---------------------------------------------------------------------------
__global__ __launch_bounds__(256) void ln_split(
    const float* __restrict__ Qb, const float* __restrict__ Kb,
    float* __restrict__ Vb, const float* __restrict__ sq,
    const float* __restrict__ bq, const float* __restrict__ sk,
    const float* __restrict__ bk, const float* __restrict__ sv,
    const float* __restrict__ bv, unsigned short* __restrict__ Qh,
    unsigned short* __restrict__ Ql, unsigned short* __restrict__ Kh,
    unsigned short* __restrict__ Kl) {
  const int z = blockIdx.y;
  const float* buf = (z == 0) ? Qb : (z == 1) ? Kb : Vb;
  const float* sc = (z == 0) ? sq : (z == 1) ? sk : sv;
  const float* bi = (z == 0) ? bq : (z == 1) ? bk : bv;

  const float* row = buf + (size_t)blockIdx.x * F_SZ;
  const int tid = threadIdx.x;
  float4 v = *(const float4*)(row + tid * 4);
  float s = v.x + v.y + v.z + v.w;
  float ss = v.x * v.x + v.y * v.y + v.z * v.z + v.w * v.w;
#pragma unroll
  for (int off = 1; off < 64; off <<= 1) {
    s += __shfl_xor(s, off, 64);
    ss += __shfl_xor(ss, off, 64);
  }
  __shared__ float red[2][4];
  if ((tid & 63) == 0) {
    red[0][tid >> 6] = s;
    red[1][tid >> 6] = ss;
  }
  __syncthreads();
  s = red[0][0] + red[0][1] + red[0][2] + red[0][3];
  ss = red[1][0] + red[1][1] + red[1][2] + red[1][3];
  const float mu = s * (1.f / F_SZ);
  const float var = ss * (1.f / F_SZ) - mu * mu;
  const float r = rsqrtf(var + 1e-6f);
  const float4 scv = *(const float4*)(sc + tid * 4);
  const float4 biv = *(const float4*)(bi + tid * 4);
  v.x = (v.x - mu) * r * scv.x + biv.x;
  v.y = (v.y - mu) * r * scv.y + biv.y;
  v.z = (v.z - mu) * r * scv.z + biv.z;
  v.w = (v.w - mu) * r * scv.w + biv.w;
  if (z == 2) {
    *(float4*)((float*)row + tid * 4) = v;
  } else {
    unsigned short* dh = (z == 0) ? Qh : Kh;
    unsigned short* dl = (z == 0) ? Ql : Kl;
    ushort4 h4, l4;
    split1(v.x, h4.x, l4.x);
    split1(v.y, h4.y, l4.y);
    split1(v.z, h4.z, l4.z);
    split1(v.w, h4.w, l4.w);
    const size_t o = (size_t)blockIdx.x * F_SZ + tid * 4;
    *(ushort4*)(dh + o) = h4;
    *(ushort4*)(dl + o) = l4;
  }
}

// ---------------------------------------------------------------------------
// V transpose + split: Vb[b][l][h*64+d] f32 -> Vth/Vtl[(b*16+h)*64+d][l] bf16.
// Block = (ltile of 64, h, b), 64x64 tile through LDS.
// ---------------------------------------------------------------------------
__global__ __launch_bounds__(256) void split_vt(
    const float* __restrict__ Vb, unsigned short* __restrict__ Vth,
    unsigned short* __restrict__ Vtl) {
  __shared__ float t[64][68];
  const int l0 = blockIdx.x * 64;
  const int h = blockIdx.y, b = blockIdx.z;
  const int tid = threadIdx.x;
  const int r = tid >> 2, c0 = (tid & 3) * 16;
  const float* src = Vb + (size_t)(b * L_SZ + l0 + r) * F_SZ + h * D_SZ + c0;
#pragma unroll
  for (int c = 0; c < 4; ++c) {
    const float4 v = *(const float4*)(src + c * 4);
    t[r][c0 + c * 4 + 0] = v.x;
    t[r][c0 + c * 4 + 1] = v.y;
    t[r][c0 + c * 4 + 2] = v.z;
    t[r][c0 + c * 4 + 3] = v.w;
  }
  __syncthreads();
  const int d = tid >> 2, lc = (tid & 3) * 16;
  unsigned short* oh =
      Vth + ((size_t)(b * H_SZ + h) * D_SZ + d) * L_SZ + l0 + lc;
  unsigned short* ol =
      Vtl + ((size_t)(b * H_SZ + h) * D_SZ + d) * L_SZ + l0 + lc;
#pragma unroll
  for (int c = 0; c < 4; ++c) {
    ushort4 h4, l4;
    split1(t[lc + c * 4 + 0][d], h4.x, l4.x);
    split1(t[lc + c * 4 + 1][d], h4.y, l4.y);
    split1(t[lc + c * 4 + 2][d], h4.z, l4.z);
    split1(t[lc + c * 4 + 3][d], h4.w, l4.w);
    *(ushort4*)(oh + c * 4) = h4;
    *(ushort4*)(ol + c * 4) = l4;
  }
}

// ---------------------------------------------------------------------------
// MFMA flash attention, bf16x3 (unchanged from round 9 run).
// ---------------------------------------------------------------------------
__global__ __launch_bounds__(256) void attn_mfma(
    const unsigned short* __restrict__ Qh, const unsigned short* __restrict__ Ql,
    const unsigned short* __restrict__ Kh, const unsigned short* __restrict__ Kl,
    const unsigned short* __restrict__ Vth, const unsigned short* __restrict__ Vtl,
    const float* __restrict__ mask, unsigned short* __restrict__ AOhi,
    unsigned short* __restrict__ AOlo) {
  __shared__ bf16x8 sQPh[512], sQPl[512];  // Q tiles, then per-wave P regions
  __shared__ bf16x8 sKh[512], sKl[512];
  __shared__ bf16x8 sVh[512], sVl[512];
  const int tid = threadIdx.x;
  const int lane = tid & 63, wave = tid >> 6;
  const int lg = lane >> 4, lr = lane & 15;
  const int q0 = blockIdx.x * 64;
  const int h = blockIdx.y, b = blockIdx.z;

  // ---- stage Q (wave0 -> hi, wave1 -> lo), 8 gld16 each: slot = kchunk*64+row
  if (wave < 2) {
    const unsigned short* src = ((wave == 0) ? Qh : Ql) +
                                (size_t)(b * L_SZ + q0 + lane) * F_SZ + h * D_SZ;
    bf16x8* dst = (wave == 0) ? sQPh : sQPl;
#pragma unroll
    for (int i = 0; i < 8; ++i) gld16(src + i * 8, &dst[i * 64]);
  }
  __syncthreads();
  bf16x8 qfh[2], qfl[2];  // A-fragments: row = wave*16+lr, kchunk = ks*4+lg
#pragma unroll
  for (int ks = 0; ks < 2; ++ks) {
    qfh[ks] = sQPh[(ks * 4 + lg) * 64 + wave * 16 + lr];
    qfl[ks] = sQPl[(ks * 4 + lg) * 64 + wave * 16 + lr];
  }
  __syncthreads();  // all Q reads done; region becomes P

  unsigned short* Ph = (unsigned short*)(sQPh + wave * 128);
  unsigned short* Pl = (unsigned short*)(sQPl + wave * 128);

  float mrow[4], lrow[4];
  f32x4 o[4];
#pragma unroll
  for (int r = 0; r < 4; ++r) {
    mrow[r] = -3.0e38f;
    lrow[r] = 0.f;
  }
#pragma unroll
  for (int j = 0; j < 4; ++j) o[j] = {0.f, 0.f, 0.f, 0.f};

  for (int kt = 0; kt < 16; ++kt) {
    const int k0 = kt * 64;
    __syncthreads();  // prev tile's K/V/P reads complete
    {                 // wave w stages one of {Kh,Kl,Vth,Vtl}
      const unsigned short* src;
      bf16x8* dst;
      if (wave == 0) {
        src = Kh + (size_t)(b * L_SZ + k0 + lane) * F_SZ + h * D_SZ;
        dst = sKh;
      } else if (wave == 1) {
        src = Kl + (size_t)(b * L_SZ + k0 + lane) * F_SZ + h * D_SZ;
        dst = sKl;
      } else if (wave == 2) {
        src = Vth + ((size_t)(b * H_SZ + h) * D_SZ + lane) * L_SZ + k0;
        dst = sVh;
      } else {
        src = Vtl + ((size_t)(b * H_SZ + h) * D_SZ + lane) * L_SZ + k0;
        dst = sVl;
      }
#pragma unroll
      for (int i = 0; i < 8; ++i) gld16(src + i * 8, &dst[i * 64]);
    }
    __syncthreads();  // vmcnt drained by compiler before barrier

    // ---- S = Q K^T (x3), 4 col-fragments of 16 keys
    f32x4 s[4];
#pragma unroll
    for (int j = 0; j < 4; ++j) s[j] = {0.f, 0.f, 0.f, 0.f};
#pragma unroll
    for (int ks = 0; ks < 2; ++ks)
#pragma unroll
      for (int j = 0; j < 4; ++j) {
        const bf16x8 kfh = sKh[(ks * 4 + lg) * 64 + j * 16 + lr];
        const bf16x8 kfl = sKl[(ks * 4 + lg) * 64 + j * 16 + lr];
        s[j] = MFMA16(qfh[ks], kfh, s[j]);
        s[j] = MFMA16(qfh[ks], kfl, s[j]);
        s[j] = MFMA16(qfl[ks], kfh, s[j]);
      }

    // ---- online softmax (fp32) + P -> LDS (hi/lo, A-fragment layout)
#pragma unroll
    for (int r = 0; r < 4; ++r) {
      const float* mp =
          mask + (size_t)(q0 + wave * 16 + lg * 4 + r) * L_SZ + k0;
      float sc[4];
#pragma unroll
      for (int j = 0; j < 4; ++j) sc[j] = s[j][r] * 0.125f + mp[j * 16 + lr];
      float mx = fmaxf(fmaxf(sc[0], sc[1]), fmaxf(sc[2], sc[3]));
#pragma unroll
      for (int off = 1; off < 16; off <<= 1)
        mx = fmaxf(mx, __shfl_xor(mx, off, 64));
      const float mnew = fmaxf(mrow[r], mx);
      const float alpha = __expf(mrow[r] - mnew);
      mrow[r] = mnew;
      float rs = 0.f;
#pragma unroll
      for (int j = 0; j < 4; ++j) {
        sc[j] = __expf(sc[j] - mnew);
        rs += sc[j];
      }
#pragma unroll
      for (int off = 1; off < 16; off <<= 1) rs += __shfl_xor(rs, off, 64);
      lrow[r] = lrow[r] * alpha + rs;
#pragma unroll
      for (int j = 0; j < 4; ++j) o[j][r] *= alpha;
#pragma unroll
      for (int j = 0; j < 4; ++j) {
        const int key = j * 16 + lr;       // C layout: col = lane&15
        const int row = lg * 4 + r;        // row = (lane>>4)*4 + reg
        const int idx = (key >> 3) * 128 + row * 8 + (key & 7);
        unsigned short hh, ll;
        split1(sc[j], hh, ll);
        Ph[idx] = hh;
        Pl[idx] = ll;
      }
    }

    // ---- O += P V (x3); A = P (rows=q, k=keys), B = Vt (rows=d, k=keys)
#pragma unroll
    for (int ks = 0; ks < 2; ++ks) {
      const bf16x8 pfh = ((bf16x8*)Ph)[(ks * 4 + lg) * 16 + lr];
      const bf16x8 pfl = ((bf16x8*)Pl)[(ks * 4 + lg) * 16 + lr];
#pragma unroll
      for (int j = 0; j < 4; ++j) {
        const bf16x8 vfh = sVh[(ks * 4 + lg) * 64 + j * 16 + lr];
        const bf16x8 vfl = sVl[(ks * 4 + lg) * 64 + j * 16 + lr];
        o[j] = MFMA16(pfh, vfh, o[j]);
        o[j] = MFMA16(pfh, vfl, o[j]);
        o[j] = MFMA16(pfl, vfh, o[j]);
      }
    }
  }

  // ---- epilogue: normalize, split, store
#pragma unroll
  for (int j = 0; j < 4; ++j)
#pragma unroll
    for (int r = 0; r < 4; ++r) {
      const int row = q0 + wave * 16 + lg * 4 + r;
      const int d = j * 16 + lr;
      const float val = o[j][r] / lrow[r];
      unsigned short hh, ll;
      split1(val, hh, ll);
      const size_t e = (size_t)(b * L_SZ + row) * F_SZ + h * D_SZ + d;
      AOhi[e] = hh;
      AOlo[e] = ll;
    }
}

// ---------------------------------------------------------------------------
// fp32 GEMM + fp32 attention + f32 LN (round-1 fallback path, ws < 144MB)
// ---------------------------------------------------------------------------
#define BM 128
#define BN 128
#define BK 8

__device__ __forceinline__ void gemm_body(const float* __restrict__ A,
                                          const float* __restrict__ W,
                                          float* __restrict__ C) {
  alignas(16) __shared__ float As[BK][BM + 4];
  alignas(16) __shared__ float Bs[BK][BN + 4];
  const int tid = threadIdx.x;
  const int tx = tid & 15;
  const int ty = tid >> 4;
  const int bn = blockIdx.x * BN;
  const int bm = blockIdx.y * BM;

  const int a_m = tid >> 1;
  const int a_k = (tid & 1) << 2;
  const int b_k = tid >> 5;
  const int b_n = (tid & 31) << 2;

  const float* Ap = A + (size_t)(bm + a_m) * F_SZ + a_k;
  const float* Wp = W + (size_t)b_k * F_SZ + bn + b_n;

  float acc[8][8];
#pragma unroll
  for (int i = 0; i < 8; ++i)
#pragma unroll
    for (int j = 0; j < 8; ++j) acc[i][j] = 0.f;

  float4 av = *(const float4*)Ap;
  float4 bv = *(const float4*)Wp;

  for (int k0 = 0; k0 < F_SZ; k0 += BK) {
    __syncthreads();
    As[a_k + 0][a_m] = av.x;
    As[a_k + 1][a_m] = av.y;
    As[a_k + 2][a_m] = av.z;
    As[a_k + 3][a_m] = av.w;
    *(float4*)&Bs[b_k][b_n] = bv;
    __syncthreads();
    if (k0 + BK < F_SZ) {
      av = *(const float4*)(Ap + k0 + BK);
      bv = *(const float4*)(Wp + (size_t)(k0 + BK) * F_SZ);
    }
#pragma unroll
    for (int k = 0; k < BK; ++k) {
      const float4 a0 = *(const float4*)&As[k][ty * 8];
      const float4 a1 = *(const float4*)&As[k][ty * 8 + 4];
      const float4 b0 = *(const float4*)&Bs[k][tx * 8];
      const float4 b1 = *(const float4*)&Bs[k][tx * 8 + 4];
      const float ar[8] = {a0.x, a0.y, a0.z, a0.w, a1.x, a1.y, a1.z, a1.w};
      const float br[8] = {b0.x, b0.y, b0.z, b0.w, b1.x, b1.y, b1.z, b1.w};
#pragma unroll
      for (int i = 0; i < 8; ++i)
#pragma unroll
        for (int j = 0; j < 8; ++j)
          acc[i][j] = fmaf(ar[i], br[j], acc[i][j]);
    }
  }

#pragma unroll
  for (int i = 0; i < 8; ++i) {
    float* crow = C + (size_t)(bm + ty * 8 + i) * F_SZ + bn + tx * 8;
    *(float4*)crow = make_float4(acc[i][0], acc[i][1], acc[i][2], acc[i][3]);
    *(float4*)(crow + 4) = make_float4(acc[i][4], acc[i][5], acc[i][6], acc[i][7]);
  }
}

__global__ __launch_bounds__(256) void gemm_qkv(
    const float* __restrict__ q, const float* __restrict__ kv,
    const float* __restrict__ Wq, const float* __restrict__ Wk,
    const float* __restrict__ Wv, float* __restrict__ Qb,
    float* __restrict__ Kb, float* __restrict__ Vb) {
  const int z = blockIdx.z;
  const float* A = (z == 0) ? q : kv;
  const float* W = (z == 0) ? Wq : (z == 1) ? Wk : Wv;
  float* C = (z == 0) ? Qb : (z == 1) ? Kb : Vb;
  gemm_body(A, W, C);
}

__global__ __launch_bounds__(256) void gemm_one(const float* __restrict__ A,
                                                const float* __restrict__ W,
                                                float* __restrict__ C) {
  gemm_body(A, W, C);
}

__global__ __launch_bounds__(256) void ln_kernel(
    float* __restrict__ Qb, float* __restrict__ Kb, float* __restrict__ Vb,
    const float* __restrict__ sq, const float* __restrict__ bq,
    const float* __restrict__ sk, const float* __restrict__ bk,
    const float* __restrict__ sv, const float* __restrict__ bv) {
  const int z = blockIdx.y;
  float* buf = (z == 0) ? Qb : (z == 1) ? Kb : Vb;
  const float* sc = (z == 0) ? sq : (z == 1) ? sk : sv;
  const float* bi = (z == 0) ? bq : (z == 1) ? bk : bv;

  float* row = buf + (size_t)blockIdx.x * F_SZ;
  const int tid = threadIdx.x;
  float4 v = *(const float4*)(row + tid * 4);
  float s = v.x + v.y + v.z + v.w;
  float ss = v.x * v.x + v.y * v.y + v.z * v.z + v.w * v.w;
#pragma unroll
  for (int off = 1; off < 64; off <<= 1) {
    s += __shfl_xor(s, off, 64);
    ss += __shfl_xor(ss, off, 64);
  }
  __shared__ float red[2][4];
  if ((tid & 63) == 0) {
    red[0][tid >> 6] = s;
    red[1][tid >> 6] = ss;
  }
  __syncthreads();
  s = red[0][0] + red[0][1] + red[0][2] + red[0][3];
  ss = red[1][0] + red[1][1] + red[1][2] + red[1][3];
  const float mu = s * (1.f / F_SZ);
  const float var = ss * (1.f / F_SZ) - mu * mu;
  const float r = rsqrtf(var + 1e-6f);
  const float4 scv = *(const float4*)(sc + tid * 4);
  const float4 biv = *(const float4*)(bi + tid * 4);
  v.x = (v.x - mu) * r * scv.x + biv.x;
  v.y = (v.y - mu) * r * scv.y + biv.y;
  v.z = (v.z - mu) * r * scv.z + biv.z;
  v.w = (v.w - mu) * r * scv.w + biv.w;
  *(float4*)(row + tid * 4) = v;
}

__global__ __launch_bounds__(256) void attn_kernel(
    float* __restrict__ QOb, const float* __restrict__ Kb,
    const float* __restrict__ Vb, const float* __restrict__ mask) {
  alignas(16) __shared__ float Qt[64][68];
  alignas(16) __shared__ float KPt[64][68];
  alignas(16) __shared__ float Vs[64][68];
  const int tid = threadIdx.x;
  const int tx = tid & 15;
  const int ty = tid >> 4;
  const int q0 = blockIdx.x * 64;
  const int h = blockIdx.y;
  const int b = blockIdx.z;
  const size_t base = (size_t)b * L_SZ * F_SZ + (size_t)h * D_SZ;

  const int li = tid >> 2;
  const int ld = (tid & 3) << 4;

  {
    const float* qp = QOb + base + (size_t)(q0 + li) * F_SZ + ld;
#pragma unroll
    for (int c = 0; c < 4; ++c) {
      const float4 v = *(const float4*)(qp + 4 * c);
      Qt[ld + 4 * c + 0][li] = v.x;
      Qt[ld + 4 * c + 1][li] = v.y;
      Qt[ld + 4 * c + 2][li] = v.z;
      Qt[ld + 4 * c + 3][li] = v.w;
    }
  }

  float mrow[4], lrow[4], acc[4][4];
#pragma unroll
  for (int a = 0; a < 4; ++a) {
    mrow[a] = -3.0e38f;
    lrow[a] = 0.f;
#pragma unroll
    for (int c = 0; c < 4; ++c) acc[a][c] = 0.f;
  }

  float4 kr[4], vr[4];
  {
    const float* kp = Kb + base + (size_t)li * F_SZ + ld;
    const float* vp = Vb + base + (size_t)li * F_SZ + ld;
#pragma unroll
    for (int c = 0; c < 4; ++c) {
      kr[c] = *(const float4*)(kp + 4 * c);
      vr[c] = *(const float4*)(vp + 4 * c);
    }
  }

  for (int kt = 0; kt < 16; ++kt) {
    const int k0 = kt * 64;
    __syncthreads();
#pragma unroll
    for (int c = 0; c < 4; ++c) {
      KPt[ld + 4 * c + 0][li] = kr[c].x;
      KPt[ld + 4 * c + 1][li] = kr[c].y;
      KPt[ld + 4 * c + 2][li] = kr[c].z;
      KPt[ld + 4 * c + 3][li] = kr[c].w;
      *(float4*)&Vs[li][ld + 4 * c] = vr[c];
    }
    __syncthreads();
    if (kt < 15) {
      const float* kp = Kb + base + (size_t)(k0 + 64 + li) * F_SZ + ld;
      const float* vp = Vb + base + (size_t)(k0 + 64 + li) * F_SZ + ld;
#pragma unroll
      for (int c = 0; c < 4; ++c) {
        kr[c] = *(const float4*)(kp + 4 * c);
        vr[c] = *(const float4*)(vp + 4 * c);
      }
    }
    float s[4][4];
#pragma unroll
    for (int a = 0; a < 4; ++a)
#pragma unroll
      for (int j = 0; j < 4; ++j) s[a][j] = 0.f;
#pragma unroll 8
    for (int d = 0; d < 64; ++d) {
      const float4 qv = *(const float4*)&Qt[d][ty * 4];
      const float4 kv = *(const float4*)&KPt[d][tx * 4];
      const float ar[4] = {qv.x, qv.y, qv.z, qv.w};
      const float br[4] = {kv.x, kv.y, kv.z, kv.w};
#pragma unroll
      for (int a = 0; a < 4; ++a)
#pragma unroll
        for (int j = 0; j < 4; ++j) s[a][j] = fmaf(ar[a], br[j], s[a][j]);
    }
    __syncthreads();

#pragma unroll
    for (int a = 0; a < 4; ++a) {
      const float4 mk =
          *(const float4*)(mask + (size_t)(q0 + ty * 4 + a) * L_SZ + k0 + tx * 4);
      s[a][0] = fmaf(s[a][0], 0.125f, mk.x);
      s[a][1] = fmaf(s[a][1], 0.125f, mk.y);
      s[a][2] = fmaf(s[a][2], 0.125f, mk.z);
      s[a][3] = fmaf(s[a][3], 0.125f, mk.w);
      float mx = fmaxf(fmaxf(s[a][0], s[a][1]), fmaxf(s[a][2], s[a][3]));
#pragma unroll
      for (int off = 1; off < 16; off <<= 1)
        mx = fmaxf(mx, __shfl_xor(mx, off, 64));
      const float mnew = fmaxf(mrow[a], mx);
      const float alpha = __expf(mrow[a] - mnew);
      mrow[a] = mnew;
      float rs = 0.f;
#pragma unroll
      for (int j = 0; j < 4; ++j) {
        s[a][j] = __expf(s[a][j] - mnew);
        rs += s[a][j];
      }
#pragma unroll
      for (int off = 1; off < 16; off <<= 1) rs += __shfl_xor(rs, off, 64);
      lrow[a] = lrow[a] * alpha + rs;
#pragma unroll
      for (int c = 0; c < 4; ++c) acc[a][c] *= alpha;
#pragma unroll
      for (int j = 0; j < 4; ++j) KPt[tx * 4 + j][ty * 4 + a] = s[a][j];
    }
    __syncthreads();

#pragma unroll 8
    for (int j = 0; j < 64; ++j) {
      const float4 pv = *(const float4*)&KPt[j][ty * 4];
      const float4 vv = *(const float4*)&Vs[j][tx * 4];
      const float pr[4] = {pv.x, pv.y, pv.z, pv.w};
      const float vc[4] = {vv.x, vv.y, vv.z, vv.w};
#pragma unroll
      for (int a = 0; a < 4; ++a)
#pragma unroll
        for (int c = 0; c < 4; ++c) acc[a][c] = fmaf(pr[a], vc[c], acc[a][c]);
    }
  }

#pragma unroll
  for (int a = 0; a < 4; ++a) {
    const float inv = 1.f / lrow[a];
    *(float4*)(QOb + base + (size_t)(q0 + ty * 4 + a) * F_SZ + tx * 4) =
        make_float4(acc[a][0] * inv, acc[a][1] * inv, acc[a][2] * inv,
                    acc[a][3] * inv);
  }
}

// ---------------------------------------------------------------------------
extern "C" void kernel_launch(void* const* d_in, const int* in_sizes, int n_in,
                              void* d_out, int out_size, void* d_ws,
                              size_t ws_size, hipStream_t stream) {
  const float* kv = (const float*)d_in[0];
  const float* q = (const float*)d_in[1];
  const float* mask = (const float*)d_in[2];
  const float* Wq = (const float*)d_in[3];
  const float* Wk = (const float*)d_in[4];
  const float* Wv = (const float*)d_in[5];
  const float* Wo = (const float*)d_in[6];
  const float* lqs = (const float*)d_in[7];
  const float* lqb = (const float*)d_in[8];
  const float* lks = (const float*)d_in[9];
  const float* lkb = (const float*)d_in[10];
  const float* lvs = (const float*)d_in[11];
  const float* lvb = (const float*)d_in[12];
  float* out = (float*)d_out;

  const size_t MB = 1024 * 1024;
  float* Qb = (float*)d_ws;                       // [0,32) MB
  float* Kb = Qb + (size_t)M_SZ * F_SZ;           // [32,64)
  float* Vb = Kb + (size_t)M_SZ * F_SZ;           // [64,96)

  if (ws_size >= 144 * MB) {
    // region D [96,128): QKV-GEMM inputs kvh/kvl, then Qh/Ql after LN
    unsigned short* kvh = (unsigned short*)((char*)d_ws + 96 * MB);
    unsigned short* kvl = kvh + (size_t)M_SZ * F_SZ;
    // region E [128,144): weight splits (persistent)
    unsigned short* Whi = (unsigned short*)((char*)d_ws + 128 * MB);
    unsigned short* Wlo = (unsigned short*)((char*)d_ws + 136 * MB);
    // d_out: qh/ql for QKV GEMM, then Kh/Kl after LN, then final output
    unsigned short* qh = (unsigned short*)d_out;
    unsigned short* ql = qh + (size_t)M_SZ * F_SZ;
    unsigned short* Qhs = kvh;                     // [96,112): Q hi (post-LN)
    unsigned short* Qls = kvl;                     // [112,128): Q lo
    unsigned short* Khs = (unsigned short*)d_out;  // Kh over dead qh
    unsigned short* Kls = Khs + (size_t)M_SZ * F_SZ;
    unsigned short* Vth = (unsigned short*)d_ws;   // [0,16): over dead Qb f32
    unsigned short* Vtl = Vth + (size_t)M_SZ * F_SZ;  // [16,32)
    unsigned short* AOhi = (unsigned short*)Kb;    // [32,48): over dead Kb f32
    unsigned short* AOlo = AOhi + (size_t)M_SZ * F_SZ;  // [48,64)

    split_w<<<dim3(32, 32, 4), 256, 0, stream>>>(Wq, Wk, Wv, Wo, Whi, Wlo);
    split_a<<<dim3((M_SZ * F_SZ) / 1024, 2), 256, 0, stream>>>(kv, q, kvh, kvl,
                                                               qh, ql);
    gemm_x3_qkv<<<dim3(F_SZ / 128, M_SZ / 128, 3), 256, 0, stream>>>(
        qh, ql, kvh, kvl, Whi, Wlo, Qb, Kb, Vb);
    // LN: z=0 Qb -> Qhs/Qls, z=1 Kb -> Khs/Kls (d_out), z=2 Vb in place
    ln_split<<<dim3(M_SZ, 3), 256, 0, stream>>>(Qb, Kb, Vb, lqs, lqb, lks, lkb,
                                                lvs, lvb, Qhs, Qls, Khs, Kls);
    // V transpose+split into [0,32) (Qb f32 dead after ln_split)
    split_vt<<<dim3(L_SZ / 64, H_SZ, B_SZ), 256, 0, stream>>>(Vb, Vth, Vtl);
    // MFMA attention -> AO hi/lo into [32,64) (Kb f32 dead)
    attn_mfma<<<dim3(L_SZ / 64, H_SZ, B_SZ), 256, 0, stream>>>(
        Qhs, Qls, Khs, Kls, Vth, Vtl, mask, AOhi, AOlo);
    // output projection (overwrites dead Kh/Kl in d_out)
    gemm_x3_one<<<dim3(F_SZ / 128, M_SZ / 128, 1), 256, 0, stream>>>(
        AOhi, AOlo, Whi + (size_t)3 * 1024 * 1024, Wlo + (size_t)3 * 1024 * 1024,
        out);
  } else {
    // fallback: round-1 fp32 path (96 MB ws)
    gemm_qkv<<<dim3(F_SZ / BN, M_SZ / BM, 3), 256, 0, stream>>>(
        q, kv, Wq, Wk, Wv, Qb, Kb, Vb);
    ln_kernel<<<dim3(M_SZ, 3), 256, 0, stream>>>(Qb, Kb, Vb, lqs, lqb, lks, lkb,
                                                 lvs, lvb);
    attn_kernel<<<dim3(L_SZ / 64, H_SZ, B_SZ), 256, 0, stream>>>(Qb, Kb, Vb,
                                                                 mask);
    gemm_one<<<dim3(F_SZ / BN, M_SZ / BM, 1), 256, 0, stream>>>(Qb, Wo, out);
  }
}

// Round 12
// 616.190 us; speedup vs baseline: 2.4187x; 1.5893x over previous
//
#include <hip/hip_runtime.h>
#include <cstdint>
#include <cstddef>

// Problem constants
#define B_SZ 8
#define L_SZ 1024
#define F_SZ 1024
#define H_SZ 16
#define D_SZ 64
#define M_SZ (B_SZ * L_SZ)  // 8192 rows

typedef __attribute__((ext_vector_type(8))) short bf16x8;
typedef __attribute__((ext_vector_type(4))) float f32x4;

// ---------------------------------------------------------------------------
// fp32 -> (hi, lo) bf16 split. hi = truncated top-16 bits (exact residual),
// lo = RNE-bf16 of (x - hi). x ~= hi + lo with ~2^-17 relative error.
// ---------------------------------------------------------------------------
__device__ __forceinline__ void split1(float x, unsigned short& h,
                                       unsigned short& l) {
  const unsigned xb = __float_as_uint(x);
  h = (unsigned short)(xb >> 16);
  const float lf = x - __uint_as_float(xb & 0xFFFF0000u);
  const unsigned lb = __float_as_uint(lf);
  l = (unsigned short)((lb + 0x7FFFu + ((lb >> 16) & 1u)) >> 16);
}

__device__ __forceinline__ void gld16(const void* g, void* l) {
  __builtin_amdgcn_global_load_lds(
      (const __attribute__((address_space(1))) void*)g,
      (__attribute__((address_space(3))) void*)l, 16, 0, 0);
}

#define MFMA16(a, b, c) __builtin_amdgcn_mfma_f32_16x16x32_bf16((a), (b), (c), 0, 0, 0)

// ===========================================================================
// PACKED LAYOUTS (R10 post-mortem: row-strided gld16 = 64-line gather per
// instruction -> ~14.6 TB/s of scattered L2 traffic capped GEMM at MfmaUtil
// 15%. All staged operands are repacked so each gld16 reads 1KB contiguous.)
//  - GEMM operand (A or B), per 128-row panel p, k-chunk c (8 bf16), row r:
//      off = (p*128 + c)*1024 + r*8          [ushort units]
//  - attn Q/K per (b,h): off = bh*65536 + (dchunk*1024 + l)*8
//  - attn Vt per (b,h):  off = bh*65536 + (kchunk*64 + d)*8
// ===========================================================================

// ---------------------------------------------------------------------------
// bf16x3 MFMA GEMM, double-buffered, coalesced packed staging.
// ---------------------------------------------------------------------------
__device__ __forceinline__ void stage_tile(const unsigned short* gp0,
                                           bf16x8* dst, int k0) {
#pragma unroll
  for (int q = 0; q < 8; ++q) {
    // chunk c = k0/8 + (q>>1), rows (q&1)*64 + lane; contiguous 1KB per gld16
    const unsigned short* gp =
        gp0 + (size_t)((k0 >> 3) + (q >> 1)) * 1024 + (q & 1) * 512;
    gld16(gp, &dst[q * 64]);
  }
}

__device__ __forceinline__ void gemm_x3_body(const unsigned short* __restrict__ Ah,
                                             const unsigned short* __restrict__ Al,
                                             const unsigned short* __restrict__ Bh,
                                             const unsigned short* __restrict__ Bl,
                                             float* __restrict__ C) {
  __shared__ bf16x8 sT[2][4][512];  // dbuf x {Ahi, Alo, Bhi, Blo} x 8KB
  const int tid = threadIdx.x;
  const int lane = tid & 63;
  const int wave = tid >> 6;
  const int wr = wave >> 1, wc = wave & 1;
  const int lg = lane >> 4, lr = lane & 15;
  const int bn = blockIdx.x * 128;
  const int bm = blockIdx.y * 128;

  // staging: wave w owns tile w (0:Ahi 1:Alo 2:Bhi 3:Blo); packed panel base
  const unsigned short* gsrc = (wave == 0) ? Ah
                               : (wave == 1) ? Al
                               : (wave == 2) ? Bh
                                             : Bl;
  const int panel = (wave < 2) ? (int)blockIdx.y : (int)blockIdx.x;
  const unsigned short* gw = gsrc + (size_t)panel * 131072 + lane * 8;

  f32x4 acc[4][4];
#pragma unroll
  for (int i = 0; i < 4; ++i)
#pragma unroll
    for (int j = 0; j < 4; ++j) acc[i][j] = {0.f, 0.f, 0.f, 0.f};

  // prologue: stage tile 0 into buf 0 and drain
  stage_tile(gw, sT[0][wave], 0);
  __syncthreads();

  for (int kt = 0; kt < 32; ++kt) {
    const int cur = kt & 1;

    bf16x8 ah[4], al[4], bh[4], bl[4];
#pragma unroll
    for (int i = 0; i < 4; ++i) {
      const int s = lg * 128 + wr * 64 + i * 16 + lr;
      ah[i] = sT[cur][0][s];
      al[i] = sT[cur][1][s];
    }
#pragma unroll
    for (int j = 0; j < 4; ++j) {
      const int s = lg * 128 + wc * 64 + j * 16 + lr;
      bh[j] = sT[cur][2][s];
      bl[j] = sT[cur][3][s];
    }

    // prefetch next K-tile into the other buffer; lands during MFMA phase
    if (kt < 31) stage_tile(gw, sT[cur ^ 1][wave], (kt + 1) * 32);

#pragma unroll
    for (int i = 0; i < 4; ++i)
#pragma unroll
      for (int j = 0; j < 4; ++j) {
        acc[i][j] = MFMA16(ah[i], bh[j], acc[i][j]);
        acc[i][j] = MFMA16(ah[i], bl[j], acc[i][j]);
        acc[i][j] = MFMA16(al[i], bh[j], acc[i][j]);
      }

    __syncthreads();
  }

  // C/D layout: col = lane&15, row = (lane>>4)*4 + reg
  const int r0 = bm + wr * 64 + lg * 4;
  const int c0 = bn + wc * 64 + lr;
#pragma unroll
  for (int i = 0; i < 4; ++i)
#pragma unroll
    for (int j = 0; j < 4; ++j) {
      float* cp = C + (size_t)(r0 + i * 16) * 1024 + c0 + j * 16;
      cp[0] = acc[i][j][0];
      cp[1024] = acc[i][j][1];
      cp[2048] = acc[i][j][2];
      cp[3072] = acc[i][j][3];
    }
}

__global__ __launch_bounds__(256) void gemm_x3_qkv(
    const unsigned short* __restrict__ qh, const unsigned short* __restrict__ ql,
    const unsigned short* __restrict__ kvh, const unsigned short* __restrict__ kvl,
    const unsigned short* __restrict__ Whi, const unsigned short* __restrict__ Wlo,
    float* __restrict__ Qb, float* __restrict__ Kb, float* __restrict__ Vb) {
  const int z = blockIdx.z;
  const unsigned short* Ah = (z == 0) ? qh : kvh;
  const unsigned short* Al = (z == 0) ? ql : kvl;
  const unsigned short* Bh = Whi + (size_t)z * (1024 * 1024);
  const unsigned short* Bl = Wlo + (size_t)z * (1024 * 1024);
  float* C = (z == 0) ? Qb : (z == 1) ? Kb : Vb;
  gemm_x3_body(Ah, Al, Bh, Bl, C);
}

__global__ __launch_bounds__(256) void gemm_x3_one(
    const unsigned short* __restrict__ Ah, const unsigned short* __restrict__ Al,
    const unsigned short* __restrict__ Bh, const unsigned short* __restrict__ Bl,
    float* __restrict__ C) {
  gemm_x3_body(Ah, Al, Bh, Bl, C);
}

// ---------------------------------------------------------------------------
// Weight split into packed B layout. Block = (n-panel pn, k-block of 32, z).
// Phase1: coalesced read W[k][n] -> LDS; Phase2: chunk-gather, coalesced write.
// ---------------------------------------------------------------------------
__global__ __launch_bounds__(256) void split_w(
    const float* __restrict__ Wq, const float* __restrict__ Wk,
    const float* __restrict__ Wv, const float* __restrict__ Wo,
    unsigned short* __restrict__ Whi, unsigned short* __restrict__ Wlo) {
  __shared__ float t[32][129];
  const int z = blockIdx.z;
  const float* W = (z == 0) ? Wq : (z == 1) ? Wk : (z == 2) ? Wv : Wo;
  unsigned short* oh = Whi + (size_t)z * (1024 * 1024);
  unsigned short* ol = Wlo + (size_t)z * (1024 * 1024);
  const int pn = blockIdx.x;        // n panel 0..7
  const int k0b = blockIdx.y * 32;  // k base
  const int tid = threadIdx.x;
#pragma unroll
  for (int m = 0; m < 4; ++m) {
    const int idx = m * 256 + tid;
    const int k_l = idx >> 5;  // 0..31
    const int f4 = idx & 31;   // 0..31
    const float4 v =
        *(const float4*)&W[(size_t)(k0b + k_l) * 1024 + pn * 128 + f4 * 4];
    t[k_l][f4 * 4 + 0] = v.x;
    t[k_l][f4 * 4 + 1] = v.y;
    t[k_l][f4 * 4 + 2] = v.z;
    t[k_l][f4 * 4 + 3] = v.w;
  }
  __syncthreads();
#pragma unroll
  for (int m = 0; m < 2; ++m) {
    const int id = m * 256 + tid;
    const int rn = id & 127;   // n within panel
    const int c_l = id >> 7;   // 0..3 local k-chunk
    alignas(16) unsigned short hb[8], lb[8];
#pragma unroll
    for (int i = 0; i < 8; ++i) split1(t[c_l * 8 + i][rn], hb[i], lb[i]);
    const size_t off =
        ((size_t)(pn * 128 + (k0b >> 3) + c_l) << 10) + rn * 8;
    *(float4*)&oh[off] = *(const float4*)hb;
    *(float4*)&ol[off] = *(const float4*)lb;
  }
}

// ---------------------------------------------------------------------------
// A-matrix split into packed A layout. Block = (k-block 32, row-panel, z).
// ---------------------------------------------------------------------------
__global__ __launch_bounds__(256) void split_a(
    const float* __restrict__ kv, const float* __restrict__ q,
    unsigned short* __restrict__ kvh, unsigned short* __restrict__ kvl,
    unsigned short* __restrict__ qh, unsigned short* __restrict__ ql) {
  __shared__ float t[128][33];
  const int z = blockIdx.z;
  const float* src = (z == 0) ? kv : q;
  unsigned short* dh = (z == 0) ? kvh : qh;
  unsigned short* dl = (z == 0) ? kvl : ql;
  const int p = blockIdx.y;         // row panel 0..63
  const int k0b = blockIdx.x * 32;  // k base
  const int tid = threadIdx.x;
#pragma unroll
  for (int m = 0; m < 4; ++m) {
    const int idx = m * 256 + tid;
    const int r_l = idx >> 3;  // 0..127
    const int f4 = idx & 7;    // 0..7
    const float4 v =
        *(const float4*)&src[(size_t)(p * 128 + r_l) * 1024 + k0b + f4 * 4];
    t[r_l][f4 * 4 + 0] = v.x;
    t[r_l][f4 * 4 + 1] = v.y;
    t[r_l][f4 * 4 + 2] = v.z;
    t[r_l][f4 * 4 + 3] = v.w;
  }
  __syncthreads();
#pragma unroll
  for (int m = 0; m < 2; ++m) {
    const int id = m * 256 + tid;
    const int r = id & 127;
    const int c_l = id >> 7;  // 0..3
    alignas(16) unsigned short hb[8], lb[8];
#pragma unroll
    for (int i = 0; i < 8; ++i) split1(t[r][c_l * 8 + i], hb[i], lb[i]);
    const size_t off = ((size_t)(p * 128 + (k0b >> 3) + c_l) << 10) + r * 8;
    *(float4*)&dh[off] = *(const float4*)hb;
    *(float4*)&dl[off] = *(const float4*)lb;
  }
}

// ---------------------------------------------------------------------------
// LayerNorm + split. z=0: Q -> packed per (b,h); z=1: K -> packed per (b,h);
// z=2: V in-place f32 (packed later by split_vt).
// Packed: off = bh*65536 + (dchunk*1024 + l)*8 + pos.
// ---------------------------------------------------------------------------
__global__ __launch_bounds__(256) void ln_split(
    const float* __restrict__ Qb, const float* __restrict__ Kb,
    float* __restrict__ Vb, const float* __restrict__ sq,
    const float* __restrict__ bq, const float* __restrict__ sk,
    const float* __restrict__ bk, const float* __restrict__ sv,
    const float* __restrict__ bv, unsigned short* __restrict__ Qh,
    unsigned short* __restrict__ Ql, unsigned short* __restrict__ Kh,
    unsigned short* __restrict__ Kl) {
  const int z = blockIdx.y;
  const float* buf = (z == 0) ? Qb : (z == 1) ? Kb : Vb;
  const float* sc = (z == 0) ? sq : (z == 1) ? sk : sv;
  const float* bi = (z == 0) ? bq : (z == 1) ? bk : bv;

  const float* row = buf + (size_t)blockIdx.x * F_SZ;
  const int tid = threadIdx.x;
  float4 v = *(const float4*)(row + tid * 4);
  float s = v.x + v.y + v.z + v.w;
  float ss = v.x * v.x + v.y * v.y + v.z * v.z + v.w * v.w;
#pragma unroll
  for (int off = 1; off < 64; off <<= 1) {
    s += __shfl_xor(s, off, 64);
    ss += __shfl_xor(ss, off, 64);
  }
  __shared__ float red[2][4];
  if ((tid & 63) == 0) {
    red[0][tid >> 6] = s;
    red[1][tid >> 6] = ss;
  }
  __syncthreads();
  s = red[0][0] + red[0][1] + red[0][2] + red[0][3];
  ss = red[1][0] + red[1][1] + red[1][2] + red[1][3];
  const float mu = s * (1.f / F_SZ);
  const float var = ss * (1.f / F_SZ) - mu * mu;
  const float r = rsqrtf(var + 1e-6f);
  const float4 scv = *(const float4*)(sc + tid * 4);
  const float4 biv = *(const float4*)(bi + tid * 4);
  v.x = (v.x - mu) * r * scv.x + biv.x;
  v.y = (v.y - mu) * r * scv.y + biv.y;
  v.z = (v.z - mu) * r * scv.z + biv.z;
  v.w = (v.w - mu) * r * scv.w + biv.w;
  if (z == 2) {
    *(float4*)((float*)row + tid * 4) = v;
  } else {
    unsigned short* dh = (z == 0) ? Qh : Kh;
    unsigned short* dl = (z == 0) ? Ql : Kl;
    ushort4 h4, l4;
    split1(v.x, h4.x, l4.x);
    split1(v.y, h4.y, l4.y);
    split1(v.z, h4.z, l4.z);
    split1(v.w, h4.w, l4.w);
    // feature index k = tid*4: head = tid>>4, dchunk = (tid>>1)&7, pos=(tid&1)*4
    const int b = blockIdx.x >> 10, l = blockIdx.x & 1023;
    const int hh_ = tid >> 4;
    const int c_h = (tid >> 1) & 7;
    const int pos = (tid & 1) * 4;
    const size_t o = ((size_t)(b * H_SZ + hh_) << 16) +
                     ((size_t)c_h * 1024 + l) * 8 + pos;
    *(ushort4*)(dh + o) = h4;
    *(ushort4*)(dl + o) = l4;
  }
}

// ---------------------------------------------------------------------------
// V transpose + split into packed Vt: off = bh*65536 + (kchunk*64 + d)*8.
// Block = (ltile of 64, h, b); 64x64 tile through LDS.
// ---------------------------------------------------------------------------
__global__ __launch_bounds__(256) void split_vt(
    const float* __restrict__ Vb, unsigned short* __restrict__ Vth,
    unsigned short* __restrict__ Vtl) {
  __shared__ float t[64][68];
  const int l0 = blockIdx.x * 64;
  const int h = blockIdx.y, b = blockIdx.z;
  const int tid = threadIdx.x;
  const int r = tid >> 2, c0 = (tid & 3) * 16;
  const float* src = Vb + (size_t)(b * L_SZ + l0 + r) * F_SZ + h * D_SZ + c0;
#pragma unroll
  for (int c = 0; c < 4; ++c) {
    const float4 v = *(const float4*)(src + c * 4);
    t[r][c0 + c * 4 + 0] = v.x;
    t[r][c0 + c * 4 + 1] = v.y;
    t[r][c0 + c * 4 + 2] = v.z;
    t[r][c0 + c * 4 + 3] = v.w;
  }
  __syncthreads();
  const size_t base = (size_t)(b * H_SZ + h) << 16;
#pragma unroll
  for (int m = 0; m < 2; ++m) {
    const int id = m * 256 + tid;
    const int d = id & 63;
    const int kc_l = id >> 6;  // 0..7
    alignas(16) unsigned short hb[8], lb[8];
#pragma unroll
    for (int i = 0; i < 8; ++i) split1(t[kc_l * 8 + i][d], hb[i], lb[i]);
    const size_t off = base + (size_t)((l0 >> 3) + kc_l) * 512 + d * 8;
    *(float4*)&Vth[off] = *(const float4*)hb;
    *(float4*)&Vtl[off] = *(const float4*)lb;
  }
}

// ---------------------------------------------------------------------------
// MFMA flash attention, bf16x3, coalesced packed staging.
// Output written pre-packed in GEMM-A layout for the Wo projection.
// ---------------------------------------------------------------------------
__global__ __launch_bounds__(256) void attn_mfma(
    const unsigned short* __restrict__ Qh, const unsigned short* __restrict__ Ql,
    const unsigned short* __restrict__ Kh, const unsigned short* __restrict__ Kl,
    const unsigned short* __restrict__ Vth, const unsigned short* __restrict__ Vtl,
    const float* __restrict__ mask, unsigned short* __restrict__ AOhi,
    unsigned short* __restrict__ AOlo) {
  __shared__ bf16x8 sQPh[512], sQPl[512];  // Q tiles, then per-wave P regions
  __shared__ bf16x8 sKh[512], sKl[512];
  __shared__ bf16x8 sVh[512], sVl[512];
  const int tid = threadIdx.x;
  const int lane = tid & 63, wave = tid >> 6;
  const int lg = lane >> 4, lr = lane & 15;
  const int q0 = blockIdx.x * 64;
  const int h = blockIdx.y, b = blockIdx.z;
  const size_t bh16 = (size_t)(b * H_SZ + h) << 16;

  // ---- stage Q (wave0 -> hi, wave1 -> lo): packed, 1KB contiguous per gld16
  if (wave < 2) {
    const unsigned short* src = ((wave == 0) ? Qh : Ql) + bh16;
    bf16x8* dst = (wave == 0) ? sQPh : sQPl;
#pragma unroll
    for (int i = 0; i < 8; ++i)
      gld16(src + (size_t)i * 8192 + (size_t)(q0 + lane) * 8, &dst[i * 64]);
  }
  __syncthreads();
  bf16x8 qfh[2], qfl[2];  // A-fragments: row = wave*16+lr, kchunk = ks*4+lg
#pragma unroll
  for (int ks = 0; ks < 2; ++ks) {
    qfh[ks] = sQPh[(ks * 4 + lg) * 64 + wave * 16 + lr];
    qfl[ks] = sQPl[(ks * 4 + lg) * 64 + wave * 16 + lr];
  }
  __syncthreads();  // all Q reads done; region becomes P

  unsigned short* Ph = (unsigned short*)(sQPh + wave * 128);
  unsigned short* Pl = (unsigned short*)(sQPl + wave * 128);

  float mrow[4], lrow[4];
  f32x4 o[4];
#pragma unroll
  for (int r = 0; r < 4; ++r) {
    mrow[r] = -3.0e38f;
    lrow[r] = 0.f;
  }
#pragma unroll
  for (int j = 0; j < 4; ++j) o[j] = {0.f, 0.f, 0.f, 0.f};

  for (int kt = 0; kt < 16; ++kt) {
    const int k0 = kt * 64;
    __syncthreads();  // prev tile's K/V/P reads complete
    {                 // wave w stages one of {Kh,Kl,Vth,Vtl}, packed sources
      if (wave < 2) {
        const unsigned short* src = ((wave == 0) ? Kh : Kl) + bh16;
        bf16x8* dst = (wave == 0) ? sKh : sKl;
#pragma unroll
        for (int i = 0; i < 8; ++i)
          gld16(src + (size_t)i * 8192 + (size_t)(k0 + lane) * 8, &dst[i * 64]);
      } else {
        const unsigned short* src = ((wave == 2) ? Vth : Vtl) + bh16;
        bf16x8* dst = (wave == 2) ? sVh : sVl;
#pragma unroll
        for (int i = 0; i < 8; ++i)
          gld16(src + (size_t)((k0 >> 3) + i) * 512 + (size_t)lane * 8,
                &dst[i * 64]);
      }
    }
    __syncthreads();  // vmcnt drained by compiler before barrier

    // ---- S = Q K^T (x3), 4 col-fragments of 16 keys
    f32x4 s[4];
#pragma unroll
    for (int j = 0; j < 4; ++j) s[j] = {0.f, 0.f, 0.f, 0.f};
#pragma unroll
    for (int ks = 0; ks < 2; ++ks)
#pragma unroll
      for (int j = 0; j < 4; ++j) {
        const bf16x8 kfh = sKh[(ks * 4 + lg) * 64 + j * 16 + lr];
        const bf16x8 kfl = sKl[(ks * 4 + lg) * 64 + j * 16 + lr];
        s[j] = MFMA16(qfh[ks], kfh, s[j]);
        s[j] = MFMA16(qfh[ks], kfl, s[j]);
        s[j] = MFMA16(qfl[ks], kfh, s[j]);
      }

    // ---- online softmax (fp32) + P -> LDS (hi/lo, A-fragment layout)
#pragma unroll
    for (int r = 0; r < 4; ++r) {
      const float* mp =
          mask + (size_t)(q0 + wave * 16 + lg * 4 + r) * L_SZ + k0;
      float sc[4];
#pragma unroll
      for (int j = 0; j < 4; ++j) sc[j] = s[j][r] * 0.125f + mp[j * 16 + lr];
      float mx = fmaxf(fmaxf(sc[0], sc[1]), fmaxf(sc[2], sc[3]));
#pragma unroll
      for (int off = 1; off < 16; off <<= 1)
        mx = fmaxf(mx, __shfl_xor(mx, off, 64));
      const float mnew = fmaxf(mrow[r], mx);
      const float alpha = __expf(mrow[r] - mnew);
      mrow[r] = mnew;
      float rs = 0.f;
#pragma unroll
      for (int j = 0; j < 4; ++j) {
        sc[j] = __expf(sc[j] - mnew);
        rs += sc[j];
      }
#pragma unroll
      for (int off = 1; off < 16; off <<= 1) rs += __shfl_xor(rs, off, 64);
      lrow[r] = lrow[r] * alpha + rs;
#pragma unroll
      for (int j = 0; j < 4; ++j) o[j][r] *= alpha;
#pragma unroll
      for (int j = 0; j < 4; ++j) {
        const int key = j * 16 + lr;       // C layout: col = lane&15
        const int row = lg * 4 + r;        // row = (lane>>4)*4 + reg
        const int idx = (key >> 3) * 128 + row * 8 + (key & 7);
        unsigned short hh, ll;
        split1(sc[j], hh, ll);
        Ph[idx] = hh;
        Pl[idx] = ll;
      }
    }

    // ---- O += P V (x3); A = P (rows=q, k=keys), B = Vt (rows=d, k=keys)
#pragma unroll
    for (int ks = 0; ks < 2; ++ks) {
      const bf16x8 pfh = ((bf16x8*)Ph)[(ks * 4 + lg) * 16 + lr];
      const bf16x8 pfl = ((bf16x8*)Pl)[(ks * 4 + lg) * 16 + lr];
#pragma unroll
      for (int j = 0; j < 4; ++j) {
        const bf16x8 vfh = sVh[(ks * 4 + lg) * 64 + j * 16 + lr];
        const bf16x8 vfl = sVl[(ks * 4 + lg) * 64 + j * 16 + lr];
        o[j] = MFMA16(pfh, vfh, o[j]);
        o[j] = MFMA16(pfh, vfl, o[j]);
        o[j] = MFMA16(pfl, vfh, o[j]);
      }
    }
  }

  // ---- epilogue: normalize, split, store PACKED for the Wo GEMM:
  // off = (p*128 + c)*1024 + rr*8 + pos; p = grow/128, rr = grow%128,
  // c = h*8 + j*2 + (lr>>3), pos = lr&7.
#pragma unroll
  for (int j = 0; j < 4; ++j)
#pragma unroll
    for (int r = 0; r < 4; ++r) {
      const int row = q0 + wave * 16 + lg * 4 + r;
      const int grow = b * L_SZ + row;
      const int p = grow >> 7, rr = grow & 127;
      const int c = h * 8 + j * 2 + (lr >> 3);
      const float val = o[j][r] / lrow[r];
      unsigned short hh, ll;
      split1(val, hh, ll);
      const size_t e = ((size_t)(p * 128 + c) << 10) + rr * 8 + (lr & 7);
      AOhi[e] = hh;
      AOlo[e] = ll;
    }
}

// ---------------------------------------------------------------------------
// fp32 GEMM + fp32 attention + f32 LN (round-1 fallback path, ws < 144MB)
// ---------------------------------------------------------------------------
#define BM 128
#define BN 128
#define BK 8

__device__ __forceinline__ void gemm_body(const float* __restrict__ A,
                                          const float* __restrict__ W,
                                          float* __restrict__ C) {
  alignas(16) __shared__ float As[BK][BM + 4];
  alignas(16) __shared__ float Bs[BK][BN + 4];
  const int tid = threadIdx.x;
  const int tx = tid & 15;
  const int ty = tid >> 4;
  const int bn = blockIdx.x * BN;
  const int bm = blockIdx.y * BM;

  const int a_m = tid >> 1;
  const int a_k = (tid & 1) << 2;
  const int b_k = tid >> 5;
  const int b_n = (tid & 31) << 2;

  const float* Ap = A + (size_t)(bm + a_m) * F_SZ + a_k;
  const float* Wp = W + (size_t)b_k * F_SZ + bn + b_n;

  float acc[8][8];
#pragma unroll
  for (int i = 0; i < 8; ++i)
#pragma unroll
    for (int j = 0; j < 8; ++j) acc[i][j] = 0.f;

  float4 av = *(const float4*)Ap;
  float4 bv = *(const float4*)Wp;

  for (int k0 = 0; k0 < F_SZ; k0 += BK) {
    __syncthreads();
    As[a_k + 0][a_m] = av.x;
    As[a_k + 1][a_m] = av.y;
    As[a_k + 2][a_m] = av.z;
    As[a_k + 3][a_m] = av.w;
    *(float4*)&Bs[b_k][b_n] = bv;
    __syncthreads();
    if (k0 + BK < F_SZ) {
      av = *(const float4*)(Ap + k0 + BK);
      bv = *(const float4*)(Wp + (size_t)(k0 + BK) * F_SZ);
    }
#pragma unroll
    for (int k = 0; k < BK; ++k) {
      const float4 a0 = *(const float4*)&As[k][ty * 8];
      const float4 a1 = *(const float4*)&As[k][ty * 8 + 4];
      const float4 b0 = *(const float4*)&Bs[k][tx * 8];
      const float4 b1 = *(const float4*)&Bs[k][tx * 8 + 4];
      const float ar[8] = {a0.x, a0.y, a0.z, a0.w, a1.x, a1.y, a1.z, a1.w};
      const float br[8] = {b0.x, b0.y, b0.z, b0.w, b1.x, b1.y, b1.z, b1.w};
#pragma unroll
      for (int i = 0; i < 8; ++i)
#pragma unroll
        for (int j = 0; j < 8; ++j)
          acc[i][j] = fmaf(ar[i], br[j], acc[i][j]);
    }
  }

#pragma unroll
  for (int i = 0; i < 8; ++i) {
    float* crow = C + (size_t)(bm + ty * 8 + i) * F_SZ + bn + tx * 8;
    *(float4*)crow = make_float4(acc[i][0], acc[i][1], acc[i][2], acc[i][3]);
    *(float4*)(crow + 4) = make_float4(acc[i][4], acc[i][5], acc[i][6], acc[i][7]);
  }
}

__global__ __launch_bounds__(256) void gemm_qkv(
    const float* __restrict__ q, const float* __restrict__ kv,
    const float* __restrict__ Wq, const float* __restrict__ Wk,
    const float* __restrict__ Wv, float* __restrict__ Qb,
    float* __restrict__ Kb, float* __restrict__ Vb) {
  const int z = blockIdx.z;
  const float* A = (z == 0) ? q : kv;
  const float* W = (z == 0) ? Wq : (z == 1) ? Wk : Wv;
  float* C = (z == 0) ? Qb : (z == 1) ? Kb : Vb;
  gemm_body(A, W, C);
}

__global__ __launch_bounds__(256) void gemm_one(const float* __restrict__ A,
                                                const float* __restrict__ W,
                                                float* __restrict__ C) {
  gemm_body(A, W, C);
}

__global__ __launch_bounds__(256) void ln_kernel(
    float* __restrict__ Qb, float* __restrict__ Kb, float* __restrict__ Vb,
    const float* __restrict__ sq, const float* __restrict__ bq,
    const float* __restrict__ sk, const float* __restrict__ bk,
    const float* __restrict__ sv, const float* __restrict__ bv) {
  const int z = blockIdx.y;
  float* buf = (z == 0) ? Qb : (z == 1) ? Kb : Vb;
  const float* sc = (z == 0) ? sq : (z == 1) ? sk : sv;
  const float* bi = (z == 0) ? bq : (z == 1) ? bk : bv;

  float* row = buf + (size_t)blockIdx.x * F_SZ;
  const int tid = threadIdx.x;
  float4 v = *(const float4*)(row + tid * 4);
  float s = v.x + v.y + v.z + v.w;
  float ss = v.x * v.x + v.y * v.y + v.z * v.z + v.w * v.w;
#pragma unroll
  for (int off = 1; off < 64; off <<= 1) {
    s += __shfl_xor(s, off, 64);
    ss += __shfl_xor(ss, off, 64);
  }
  __shared__ float red[2][4];
  if ((tid & 63) == 0) {
    red[0][tid >> 6] = s;
    red[1][tid >> 6] = ss;
  }
  __syncthreads();
  s = red[0][0] + red[0][1] + red[0][2] + red[0][3];
  ss = red[1][0] + red[1][1] + red[1][2] + red[1][3];
  const float mu = s * (1.f / F_SZ);
  const float var = ss * (1.f / F_SZ) - mu * mu;
  const float r = rsqrtf(var + 1e-6f);
  const float4 scv = *(const float4*)(sc + tid * 4);
  const float4 biv = *(const float4*)(bi + tid * 4);
  v.x = (v.x - mu) * r * scv.x + biv.x;
  v.y = (v.y - mu) * r * scv.y + biv.y;
  v.z = (v.z - mu) * r * scv.z + biv.z;
  v.w = (v.w - mu) * r * scv.w + biv.w;
  *(float4*)(row + tid * 4) = v;
}

__global__ __launch_bounds__(256) void attn_kernel(
    float* __restrict__ QOb, const float* __restrict__ Kb,
    const float* __restrict__ Vb, const float* __restrict__ mask) {
  alignas(16) __shared__ float Qt[64][68];
  alignas(16) __shared__ float KPt[64][68];
  alignas(16) __shared__ float Vs[64][68];
  const int tid = threadIdx.x;
  const int tx = tid & 15;
  const int ty = tid >> 4;
  const int q0 = blockIdx.x * 64;
  const int h = blockIdx.y;
  const int b = blockIdx.z;
  const size_t base = (size_t)b * L_SZ * F_SZ + (size_t)h * D_SZ;

  const int li = tid >> 2;
  const int ld = (tid & 3) << 4;

  {
    const float* qp = QOb + base + (size_t)(q0 + li) * F_SZ + ld;
#pragma unroll
    for (int c = 0; c < 4; ++c) {
      const float4 v = *(const float4*)(qp + 4 * c);
      Qt[ld + 4 * c + 0][li] = v.x;
      Qt[ld + 4 * c + 1][li] = v.y;
      Qt[ld + 4 * c + 2][li] = v.z;
      Qt[ld + 4 * c + 3][li] = v.w;
    }
  }

  float mrow[4], lrow[4], acc[4][4];
#pragma unroll
  for (int a = 0; a < 4; ++a) {
    mrow[a] = -3.0e38f;
    lrow[a] = 0.f;
#pragma unroll
    for (int c = 0; c < 4; ++c) acc[a][c] = 0.f;
  }

  float4 kr[4], vr[4];
  {
    const float* kp = Kb + base + (size_t)li * F_SZ + ld;
    const float* vp = Vb + base + (size_t)li * F_SZ + ld;
#pragma unroll
    for (int c = 0; c < 4; ++c) {
      kr[c] = *(const float4*)(kp + 4 * c);
      vr[c] = *(const float4*)(vp + 4 * c);
    }
  }

  for (int kt = 0; kt < 16; ++kt) {
    const int k0 = kt * 64;
    __syncthreads();
#pragma unroll
    for (int c = 0; c < 4; ++c) {
      KPt[ld + 4 * c + 0][li] = kr[c].x;
      KPt[ld + 4 * c + 1][li] = kr[c].y;
      KPt[ld + 4 * c + 2][li] = kr[c].z;
      KPt[ld + 4 * c + 3][li] = kr[c].w;
      *(float4*)&Vs[li][ld + 4 * c] = vr[c];
    }
    __syncthreads();
    if (kt < 15) {
      const float* kp = Kb + base + (size_t)(k0 + 64 + li) * F_SZ + ld;
      const float* vp = Vb + base + (size_t)(k0 + 64 + li) * F_SZ + ld;
#pragma unroll
      for (int c = 0; c < 4; ++c) {
        kr[c] = *(const float4*)(kp + 4 * c);
        vr[c] = *(const float4*)(vp + 4 * c);
      }
    }
    float s[4][4];
#pragma unroll
    for (int a = 0; a < 4; ++a)
#pragma unroll
      for (int j = 0; j < 4; ++j) s[a][j] = 0.f;
#pragma unroll 8
    for (int d = 0; d < 64; ++d) {
      const float4 qv = *(const float4*)&Qt[d][ty * 4];
      const float4 kv = *(const float4*)&KPt[d][tx * 4];
      const float ar[4] = {qv.x, qv.y, qv.z, qv.w};
      const float br[4] = {kv.x, kv.y, kv.z, kv.w};
#pragma unroll
      for (int a = 0; a < 4; ++a)
#pragma unroll
        for (int j = 0; j < 4; ++j) s[a][j] = fmaf(ar[a], br[j], s[a][j]);
    }
    __syncthreads();

#pragma unroll
    for (int a = 0; a < 4; ++a) {
      const float4 mk =
          *(const float4*)(mask + (size_t)(q0 + ty * 4 + a) * L_SZ + k0 + tx * 4);
      s[a][0] = fmaf(s[a][0], 0.125f, mk.x);
      s[a][1] = fmaf(s[a][1], 0.125f, mk.y);
      s[a][2] = fmaf(s[a][2], 0.125f, mk.z);
      s[a][3] = fmaf(s[a][3], 0.125f, mk.w);
      float mx = fmaxf(fmaxf(s[a][0], s[a][1]), fmaxf(s[a][2], s[a][3]));
#pragma unroll
      for (int off = 1; off < 16; off <<= 1)
        mx = fmaxf(mx, __shfl_xor(mx, off, 64));
      const float mnew = fmaxf(mrow[a], mx);
      const float alpha = __expf(mrow[a] - mnew);
      mrow[a] = mnew;
      float rs = 0.f;
#pragma unroll
      for (int j = 0; j < 4; ++j) {
        s[a][j] = __expf(s[a][j] - mnew);
        rs += s[a][j];
      }
#pragma unroll
      for (int off = 1; off < 16; off <<= 1) rs += __shfl_xor(rs, off, 64);
      lrow[a] = lrow[a] * alpha + rs;
#pragma unroll
      for (int c = 0; c < 4; ++c) acc[a][c] *= alpha;
#pragma unroll
      for (int j = 0; j < 4; ++j) KPt[tx * 4 + j][ty * 4 + a] = s[a][j];
    }
    __syncthreads();

#pragma unroll 8
    for (int j = 0; j < 64; ++j) {
      const float4 pv = *(const float4*)&KPt[j][ty * 4];
      const float4 vv = *(const float4*)&Vs[j][tx * 4];
      const float pr[4] = {pv.x, pv.y, pv.z, pv.w};
      const float vc[4] = {vv.x, vv.y, vv.z, vv.w};
#pragma unroll
      for (int a = 0; a < 4; ++a)
#pragma unroll
        for (int c = 0; c < 4; ++c) acc[a][c] = fmaf(pr[a], vc[c], acc[a][c]);
    }
  }

#pragma unroll
  for (int a = 0; a < 4; ++a) {
    const float inv = 1.f / lrow[a];
    *(float4*)(QOb + base + (size_t)(q0 + ty * 4 + a) * F_SZ + tx * 4) =
        make_float4(acc[a][0] * inv, acc[a][1] * inv, acc[a][2] * inv,
                    acc[a][3] * inv);
  }
}

// ---------------------------------------------------------------------------
extern "C" void kernel_launch(void* const* d_in, const int* in_sizes, int n_in,
                              void* d_out, int out_size, void* d_ws,
                              size_t ws_size, hipStream_t stream) {
  const float* kv = (const float*)d_in[0];
  const float* q = (const float*)d_in[1];
  const float* mask = (const float*)d_in[2];
  const float* Wq = (const float*)d_in[3];
  const float* Wk = (const float*)d_in[4];
  const float* Wv = (const float*)d_in[5];
  const float* Wo = (const float*)d_in[6];
  const float* lqs = (const float*)d_in[7];
  const float* lqb = (const float*)d_in[8];
  const float* lks = (const float*)d_in[9];
  const float* lkb = (const float*)d_in[10];
  const float* lvs = (const float*)d_in[11];
  const float* lvb = (const float*)d_in[12];
  float* out = (float*)d_out;

  const size_t MB = 1024 * 1024;
  float* Qb = (float*)d_ws;                       // [0,32) MB
  float* Kb = Qb + (size_t)M_SZ * F_SZ;           // [32,64)
  float* Vb = Kb + (size_t)M_SZ * F_SZ;           // [64,96)

  if (ws_size >= 144 * MB) {
    // region D [96,128): QKV-GEMM inputs kvh/kvl, then Q packed after LN
    unsigned short* kvh = (unsigned short*)((char*)d_ws + 96 * MB);
    unsigned short* kvl = kvh + (size_t)M_SZ * F_SZ;
    // region E [128,144): weight splits (persistent, packed)
    unsigned short* Whi = (unsigned short*)((char*)d_ws + 128 * MB);
    unsigned short* Wlo = (unsigned short*)((char*)d_ws + 136 * MB);
    // d_out: qh/ql for QKV GEMM, then K packed after LN, then final output
    unsigned short* qh = (unsigned short*)d_out;
    unsigned short* ql = qh + (size_t)M_SZ * F_SZ;
    unsigned short* Qhs = kvh;                     // [96,112): Q packed (post-LN)
    unsigned short* Qls = kvl;                     // [112,128)
    unsigned short* Khs = (unsigned short*)d_out;  // K packed over dead qh
    unsigned short* Kls = Khs + (size_t)M_SZ * F_SZ;
    unsigned short* Vth = (unsigned short*)d_ws;   // [0,16): over dead Qb f32
    unsigned short* Vtl = Vth + (size_t)M_SZ * F_SZ;  // [16,32)
    unsigned short* AOhi = (unsigned short*)Kb;    // [32,48): over dead Kb f32
    unsigned short* AOlo = AOhi + (size_t)M_SZ * F_SZ;  // [48,64)

    split_w<<<dim3(8, 32, 4), 256, 0, stream>>>(Wq, Wk, Wv, Wo, Whi, Wlo);
    split_a<<<dim3(32, 64, 2), 256, 0, stream>>>(kv, q, kvh, kvl, qh, ql);
    gemm_x3_qkv<<<dim3(F_SZ / 128, M_SZ / 128, 3), 256, 0, stream>>>(
        qh, ql, kvh, kvl, Whi, Wlo, Qb, Kb, Vb);
    // LN: z=0 Qb -> Q packed, z=1 Kb -> K packed (d_out), z=2 Vb in place
    ln_split<<<dim3(M_SZ, 3), 256, 0, stream>>>(Qb, Kb, Vb, lqs, lqb, lks, lkb,
                                                lvs, lvb, Qhs, Qls, Khs, Kls);
    // V transpose+split into [0,32) (Qb f32 dead after ln_split)
    split_vt<<<dim3(L_SZ / 64, H_SZ, B_SZ), 256, 0, stream>>>(Vb, Vth, Vtl);
    // MFMA attention -> AO packed into [32,64) (Kb f32 dead)
    attn_mfma<<<dim3(L_SZ / 64, H_SZ, B_SZ), 256, 0, stream>>>(
        Qhs, Qls, Khs, Kls, Vth, Vtl, mask, AOhi, AOlo);
    // output projection (overwrites dead K pack in d_out)
    gemm_x3_one<<<dim3(F_SZ / 128, M_SZ / 128, 1), 256, 0, stream>>>(
        AOhi, AOlo, Whi + (size_t)3 * 1024 * 1024, Wlo + (size_t)3 * 1024 * 1024,
        out);
  } else {
    // fallback: round-1 fp32 path (96 MB ws)
    gemm_qkv<<<dim3(F_SZ / BN, M_SZ / BM, 3), 256, 0, stream>>>(
        q, kv, Wq, Wk, Wv, Qb, Kb, Vb);
    ln_kernel<<<dim3(M_SZ, 3), 256, 0, stream>>>(Qb, Kb, Vb, lqs, lqb, lks, lkb,
                                                 lvs, lvb);
    attn_kernel<<<dim3(L_SZ / 64, H_SZ, B_SZ), 256, 0, stream>>>(Qb, Kb, Vb,
                                                                 mask);
    gemm_one<<<dim3(F_SZ / BN, M_SZ / BM, 1), 256, 0, stream>>>(Qb, Wo, out);
  }
}